// Round 5
// baseline (904.763 us; speedup 1.0000x reference)
//
#include <hip/hip_runtime.h>

#define N_FACES 50000
#define N_EDGES 800000
#define NB      16
#define HID     256
#define NOUT    512
#define SCAN_B  1024
#define SCAN_NB ((N_FACES + SCAN_B - 1) / SCAN_B)

// ---------- wave helpers ----------
__device__ __forceinline__ float wave_sum(float v) {
#pragma unroll
  for (int o = 32; o; o >>= 1) v += __shfl_xor(v, o, 64);
  return v;
}

// ---------- order-preserving float<->uint encoding (for atomicMax) ----------
__device__ __forceinline__ unsigned enc_ord(float v) {
  unsigned b = __float_as_uint(v);
  return (b & 0x80000000u) ? ~b : (b | 0x80000000u);
}
__device__ __forceinline__ float dec_ord(unsigned e) {
  unsigned b = (e & 0x80000000u) ? (e ^ 0x80000000u) : ~e;
  return __uint_as_float(b);
}

// ---------- CSR build ----------
__global__ void k_hist(const int* __restrict__ dst, int* __restrict__ cnt) {
  int e = blockIdx.x * blockDim.x + threadIdx.x;
  if (e < N_EDGES) atomicAdd(&cnt[dst[e]], 1);
}

// 3-phase parallel exclusive scan of cnt[N_FACES] -> row_ptr[N_FACES+1]
__global__ void k_scan1(const int* __restrict__ cnt, int* __restrict__ bsum) {
  __shared__ int sh[SCAN_B];
  int i = blockIdx.x * SCAN_B + threadIdx.x;
  sh[threadIdx.x] = (i < N_FACES) ? cnt[i] : 0;
  __syncthreads();
  for (int off = SCAN_B / 2; off; off >>= 1) {
    if (threadIdx.x < off) sh[threadIdx.x] += sh[threadIdx.x + off];
    __syncthreads();
  }
  if (threadIdx.x == 0) bsum[blockIdx.x] = sh[0];
}

__global__ void k_scan2(int* __restrict__ bsum) {  // nb <= 64, one wave
  int t = threadIdx.x;
  int v = (t < SCAN_NB) ? bsum[t] : 0;
  int inc = v;
#pragma unroll
  for (int off = 1; off < 64; off <<= 1) {
    int u = __shfl_up(inc, off, 64);
    if (t >= off) inc += u;
  }
  if (t < SCAN_NB) bsum[t] = inc - v;  // exclusive
}

__global__ void k_scan3(const int* __restrict__ cnt, const int* __restrict__ bsum,
                        int* __restrict__ row_ptr) {
  __shared__ int sh[SCAN_B];
  int i = blockIdx.x * SCAN_B + threadIdx.x;
  int v = (i < N_FACES) ? cnt[i] : 0;
  sh[threadIdx.x] = v;
  __syncthreads();
  for (int off = 1; off < SCAN_B; off <<= 1) {
    int x = (threadIdx.x >= off) ? sh[threadIdx.x - off] : 0;
    __syncthreads();
    sh[threadIdx.x] += x;
    __syncthreads();
  }
  if (i < N_FACES) row_ptr[i] = bsum[blockIdx.x] + sh[threadIdx.x] - v;
  if (i == 0) row_ptr[N_FACES] = N_EDGES;
}

// scatter edge features + src ids into CSR order AND compute per-edge LN stats
// (one lane per edge, serial over 256 cols, in-lane accumulation -> no shuffles;
//  edge-encoder weights staged in LDS, broadcast-read float4)
__global__ void k_scatter(const int* __restrict__ dst, const int* __restrict__ src,
                          const float* __restrict__ xe, const int* __restrict__ row_ptr,
                          const float* __restrict__ eW, const float* __restrict__ eB,
                          int* __restrict__ fill, float* __restrict__ csr_xe,
                          int* __restrict__ csr_src, float2* __restrict__ csr_stat) {
  __shared__ float sw[6][HID];
  __shared__ float sb[HID];
  int t0 = threadIdx.x;
  for (int i = t0; i < 6 * HID; i += 256) sw[i / HID][i % HID] = eW[i];
  for (int i = t0; i < HID; i += 256) sb[i] = eB[i];
  __syncthreads();

  int e = blockIdx.x * blockDim.x + t0;
  if (e >= N_EDGES) return;
  float z[6];
#pragma unroll
  for (int k = 0; k < 6; ++k) z[k] = xe[(size_t)e * 6 + k];
  int d = dst[e];
  int p = atomicAdd(&fill[d], 1);
  int pos = row_ptr[d] + p;
  csr_src[pos] = src[e];
#pragma unroll
  for (int k = 0; k < 6; ++k) csr_xe[(size_t)pos * 6 + k] = z[k];

  float s1 = 0.f, s2 = 0.f;
  for (int c = 0; c < HID; c += 4) {
    float4 w4 = *reinterpret_cast<const float4*>(&sb[c]);
#pragma unroll
    for (int k = 0; k < 6; ++k) {
      float4 m4 = *reinterpret_cast<const float4*>(&sw[k][c]);
      w4.x += z[k] * m4.x; w4.y += z[k] * m4.y;
      w4.z += z[k] * m4.z; w4.w += z[k] * m4.w;
    }
    w4.x = fmaxf(w4.x, 0.f); w4.y = fmaxf(w4.y, 0.f);
    w4.z = fmaxf(w4.z, 0.f); w4.w = fmaxf(w4.w, 0.f);
    s1 += (w4.x + w4.y) + (w4.z + w4.w);
    s2 += (w4.x * w4.x + w4.y * w4.y) + (w4.z * w4.z + w4.w * w4.w);
  }
  float mu = s1 * (1.f / HID);
  float rs = rsqrtf(fmaxf(s2 * (1.f / HID) - mu * mu, 0.f) + 1e-5f);
  csr_stat[pos] = make_float2(mu, rs);
}

// ---------- encoders + mean aggregation (one wave per node, no shuffles in edge loop) ----------
__global__ void k_encode(const float* __restrict__ xf, const float* __restrict__ csr_xe,
                         const float* __restrict__ fW, const float* __restrict__ fB,
                         const float* __restrict__ fG, const float* __restrict__ fBe,
                         const float* __restrict__ eW, const float* __restrict__ eB,
                         const float* __restrict__ eG, const float* __restrict__ eBe,
                         const int* __restrict__ row_ptr, const float2* __restrict__ csr_stat,
                         float* __restrict__ h) {
  int lane = threadIdx.x & 63;
  int n = blockIdx.x * 4 + (threadIdx.x >> 6);
  if (n >= N_FACES) return;

  // face encoder
  float x[7];
#pragma unroll
  for (int k = 0; k < 7; ++k) x[k] = xf[n * 7 + k];
  float y[4];
#pragma unroll
  for (int j = 0; j < 4; ++j) {
    int c = lane + 64 * j;
    float a = fB[c];
#pragma unroll
    for (int k = 0; k < 7; ++k) a += x[k] * fW[k * HID + c];
    y[j] = fmaxf(a, 0.f);
  }
  float s = y[0] + y[1] + y[2] + y[3];
  float s2 = y[0] * y[0] + y[1] * y[1] + y[2] * y[2] + y[3] * y[3];
  s = wave_sum(s); s2 = wave_sum(s2);
  float mu = s * (1.f / HID);
  float rs = rsqrtf(fmaxf(s2 * (1.f / HID) - mu * mu, 0.f) + 1e-5f);
  float hv[4];
#pragma unroll
  for (int j = 0; j < 4; ++j) {
    int c = lane + 64 * j;
    hv[j] = (y[j] - mu) * rs * fG[c] + fBe[c];
  }

  // hoist edge-encoder params into registers (loop-invariant)
  float ew[6][4], eb[4], eg[4], ebe[4];
#pragma unroll
  for (int j = 0; j < 4; ++j) {
    int c = lane + 64 * j;
    eb[j] = eB[c]; eg[j] = eG[c]; ebe[j] = eBe[c];
#pragma unroll
    for (int k = 0; k < 6; ++k) ew[k][j] = eW[k * HID + c];
  }

  int e0 = row_ptr[n], e1 = row_ptr[n + 1];
  float acc[4] = {0.f, 0.f, 0.f, 0.f};
  for (int t = e0; t < e1; ++t) {
    float2 st = csr_stat[t];
    float z[6];
#pragma unroll
    for (int k = 0; k < 6; ++k) z[k] = csr_xe[(size_t)t * 6 + k];
#pragma unroll
    for (int j = 0; j < 4; ++j) {
      float a = eb[j];
#pragma unroll
      for (int k = 0; k < 6; ++k) a += z[k] * ew[k][j];
      a = fmaxf(a, 0.f);
      acc[j] += (a - st.x) * (st.y * eg[j]) + ebe[j];
    }
  }
  float inv = (e1 > e0) ? 1.f / (float)(e1 - e0) : 0.f;
#pragma unroll
  for (int j = 0; j < 4; ++j) h[(size_t)n * HID + lane + 64 * j] = hv[j] + acc[j] * inv;
}

// ---------- f = h @ W with fused el/er epilogue (16 nodes/block, 256 threads) ----------
#define GM 16
__global__ void k_gemm_elr(const float* __restrict__ h, const float* __restrict__ W,
                           const float* __restrict__ al, const float* __restrict__ ar,
                           float* __restrict__ f, float* __restrict__ el,
                           float* __restrict__ er) {
  __shared__ float hs[GM][HID];
  int n0 = blockIdx.x * GM;
  int c = threadIdx.x;
  int lane = c & 63, wv = c >> 6;  // wv = head
#pragma unroll
  for (int m = 0; m < GM; ++m) hs[m][c] = h[(size_t)(n0 + m) * HID + c];
  __syncthreads();
  float acc[GM];
#pragma unroll
  for (int m = 0; m < GM; ++m) acc[m] = 0.f;
  for (int k = 0; k < HID; ++k) {
    float w = W[k * HID + c];
#pragma unroll
    for (int m = 0; m < GM; ++m) acc[m] += hs[m][k] * w;
  }
  float alv = al[wv * 64 + lane];
  float arv = ar[wv * 64 + lane];
#pragma unroll
  for (int m = 0; m < GM; ++m) {
    f[(size_t)(n0 + m) * HID + c] = acc[m];
    float vl = wave_sum(acc[m] * alv);
    float vr = wave_sum(acc[m] * arv);
    if (lane == 0) {
      el[(n0 + m) * 4 + wv] = vl;
      er[(n0 + m) * 4 + wv] = vr;
    }
  }
}

// ---------- GAT: single fused edge pass, 1-ahead software prefetch ----------
__global__ void k_gat(const float* __restrict__ f, const float* __restrict__ el,
                      const float* __restrict__ er, const int* __restrict__ row_ptr,
                      const int* __restrict__ csrc,
                      const float* __restrict__ bias, const float* __restrict__ g,
                      const float* __restrict__ be, float* __restrict__ h) {
  int lane = threadIdx.x & 63;
  int n = blockIdx.x * 4 + (threadIdx.x >> 6);
  if (n >= N_FACES) return;
  int e0 = row_ptr[n], e1 = row_ptr[n + 1];
  float4 ern = reinterpret_cast<const float4*>(er)[n];

  float s0 = 0.f, s1 = 0.f, s2 = 0.f, s3 = 0.f;
  float a0 = 0.f, a1 = 0.f, a2 = 0.f, a3 = 0.f;
  if (e0 < e1) {
    int sp = csrc[e0];
    float4 ep = reinterpret_cast<const float4*>(el)[sp];
    const float* fr = f + (size_t)sp * HID;
    float f0 = fr[lane], f1 = fr[lane + 64], f2 = fr[lane + 128], f3 = fr[lane + 192];
    for (int t = e0; t < e1; ++t) {
      int sn = 0; float4 en = ep;
      float g0 = 0.f, g1 = 0.f, g2 = 0.f, g3 = 0.f;
      if (t + 1 < e1) {
        sn = csrc[t + 1];
        en = reinterpret_cast<const float4*>(el)[sn];
        const float* frn = f + (size_t)sn * HID;
        g0 = frn[lane]; g1 = frn[lane + 64]; g2 = frn[lane + 128]; g3 = frn[lane + 192];
      }
      float w, p;
      w = ep.x + ern.x; w = fmaxf(w, 0.2f * w); p = __expf(w); s0 += p; a0 += f0 * p;
      w = ep.y + ern.y; w = fmaxf(w, 0.2f * w); p = __expf(w); s1 += p; a1 += f1 * p;
      w = ep.z + ern.z; w = fmaxf(w, 0.2f * w); p = __expf(w); s2 += p; a2 += f2 * p;
      w = ep.w + ern.w; w = fmaxf(w, 0.2f * w); p = __expf(w); s3 += p; a3 += f3 * p;
      ep = en; f0 = g0; f1 = g1; f2 = g2; f3 = g3;
    }
  }
  a0 *= (s0 > 0.f ? 1.f / s0 : 0.f);
  a1 *= (s1 > 0.f ? 1.f / s1 : 0.f);
  a2 *= (s2 > 0.f ? 1.f / s2 : 0.f);
  a3 *= (s3 > 0.f ? 1.f / s3 : 0.f);

  float y0 = fmaxf(a0 + bias[lane], 0.f);
  float y1 = fmaxf(a1 + bias[lane + 64], 0.f);
  float y2 = fmaxf(a2 + bias[lane + 128], 0.f);
  float y3 = fmaxf(a3 + bias[lane + 192], 0.f);
  float s = y0 + y1 + y2 + y3;
  float q = y0 * y0 + y1 * y1 + y2 * y2 + y3 * y3;
  s = wave_sum(s); q = wave_sum(q);
  float mu = s * (1.f / HID);
  float rs = rsqrtf(fmaxf(q * (1.f / HID) - mu * mu, 0.f) + 1e-5f);
  size_t base = (size_t)n * HID;
  h[base + lane]       = (y0 - mu) * rs * g[lane]       + be[lane];
  h[base + lane + 64]  = (y1 - mu) * rs * g[lane + 64]  + be[lane + 64];
  h[base + lane + 128] = (y2 - mu) * rs * g[lane + 128] + be[lane + 128];
  h[base + lane + 192] = (y3 - mu) * rs * g[lane + 192] + be[lane + 192];
}

// ---------- gate scores ----------
__global__ void k_gate(const float* __restrict__ h, const float* __restrict__ gw,
                       const float* __restrict__ gb, float* __restrict__ gate) {
  int lane = threadIdx.x & 63;
  int n = blockIdx.x * 4 + (threadIdx.x >> 6);
  if (n >= N_FACES) return;
  float4 v = reinterpret_cast<const float4*>(h)[(size_t)n * 64 + lane];
  float4 w = reinterpret_cast<const float4*>(gw)[lane];
  float p = v.x * w.x + v.y * w.y + v.z * w.z + v.w * w.w;
  p = wave_sum(p);
  if (lane == 0) gate[n] = p + gb[0];
}

// ---------- per-graph max of gate: LDS pre-reduction, then global atomics ----------
__global__ void k_gmax(const float* __restrict__ gate, const int* __restrict__ gid,
                       unsigned* __restrict__ gmax_u) {
  __shared__ unsigned sm[NB];
  int t = threadIdx.x;
  if (t < NB) sm[t] = 0u;
  __syncthreads();
  int n = blockIdx.x * blockDim.x + t;
  if (n < N_FACES) atomicMax(&sm[gid[n]], enc_ord(gate[n]));
  __syncthreads();
  if (t < NB && sm[t] != 0u) atomicMax(&gmax_u[t], sm[t]);
}

// ---------- parallel weighted pooling (unnormalized) ----------
#define PCHUNK 125
__global__ void k_psum(const float* __restrict__ h, const float* __restrict__ gate,
                       const int* __restrict__ gid, const unsigned* __restrict__ gmax_u,
                       float* __restrict__ praw, float* __restrict__ gs) {
  int t = threadIdx.x;
  int n0 = blockIdx.x * PCHUNK;
  int n1 = n0 + PCHUNK;
  if (n1 > N_FACES) n1 = N_FACES;
  if (n0 >= N_FACES) return;
  int cur = gid[n0];
  float gm = dec_ord(gmax_u[cur]);
  float acc = 0.f, wsum = 0.f;
  for (int n = n0; n < n1; ++n) {
    int g = gid[n];
    if (g != cur) {
      atomicAdd(&praw[cur * HID + t], acc);
      if (t == 0) atomicAdd(&gs[cur], wsum);
      acc = 0.f; wsum = 0.f; cur = g; gm = dec_ord(gmax_u[cur]);
    }
    float w = __expf(gate[n] - gm);
    acc += w * h[(size_t)n * HID + t];
    wsum += w;
  }
  atomicAdd(&praw[cur * HID + t], acc);
  if (t == 0) atomicAdd(&gs[cur], wsum);
}

__global__ void k_poolnorm(const float* __restrict__ praw, const float* __restrict__ gs,
                           float* __restrict__ pooled) {
  int b = blockIdx.x, c = threadIdx.x;
  pooled[b * HID + c] = praw[b * HID + c] / gs[b];
}

// ---------- output projection + LN ----------
__global__ void k_out(const float* __restrict__ pooled, const float* __restrict__ oW,
                      const float* __restrict__ oB, const float* __restrict__ oG,
                      const float* __restrict__ oBe, float* __restrict__ feat) {
  int b = blockIdx.x;
  int o = threadIdx.x;  // 512 threads
  int lane = o & 63, wid = o >> 6;
  __shared__ float p[HID];
  __shared__ float partS[8], partQ[8];
  __shared__ float shMu, shRs;
  if (o < HID) p[o] = pooled[b * HID + o];
  __syncthreads();
  float a = oB[o];
  for (int k = 0; k < HID; ++k) a += p[k] * oW[k * NOUT + o];
  float y = fmaxf(a, 0.f);
  float s = wave_sum(y), q = wave_sum(y * y);
  if (lane == 0) { partS[wid] = s; partQ[wid] = q; }
  __syncthreads();
  if (o == 0) {
    float S = 0.f, Q = 0.f;
#pragma unroll
    for (int i = 0; i < 8; ++i) { S += partS[i]; Q += partQ[i]; }
    float mu = S * (1.f / NOUT);
    shMu = mu;
    shRs = rsqrtf(fmaxf(Q * (1.f / NOUT) - mu * mu, 0.f) + 1e-5f);
  }
  __syncthreads();
  feat[b * NOUT + o] = (y - shMu) * shRs * oG[o] + oBe[o];
}

extern "C" void kernel_launch(void* const* d_in, const int* in_sizes, int n_in,
                              void* d_out, int out_size, void* d_ws, size_t ws_size,
                              hipStream_t stream) {
  (void)in_sizes; (void)n_in; (void)out_size; (void)ws_size;
  const float* x_face    = (const float*)d_in[0];
  const float* x_edge    = (const float*)d_in[1];
  const float* face_W    = (const float*)d_in[2];
  const float* face_b    = (const float*)d_in[3];
  const float* face_g    = (const float*)d_in[4];
  const float* face_beta = (const float*)d_in[5];
  const float* edge_W    = (const float*)d_in[6];
  const float* edge_b    = (const float*)d_in[7];
  const float* edge_g    = (const float*)d_in[8];
  const float* edge_beta = (const float*)d_in[9];
  const float* g0_W      = (const float*)d_in[10];
  const float* g0_al     = (const float*)d_in[11];
  const float* g0_ar     = (const float*)d_in[12];
  const float* g0_bias   = (const float*)d_in[13];
  const float* g0_g      = (const float*)d_in[14];
  const float* g0_beta   = (const float*)d_in[15];
  const float* g1_W      = (const float*)d_in[16];
  const float* g1_al     = (const float*)d_in[17];
  const float* g1_ar     = (const float*)d_in[18];
  const float* g1_bias   = (const float*)d_in[19];
  const float* g1_g      = (const float*)d_in[20];
  const float* g1_beta   = (const float*)d_in[21];
  const float* gate_W    = (const float*)d_in[22];
  const float* gate_b    = (const float*)d_in[23];
  const float* out_W     = (const float*)d_in[24];
  const float* out_b     = (const float*)d_in[25];
  const float* out_g     = (const float*)d_in[26];
  const float* out_beta  = (const float*)d_in[27];
  const int*   src       = (const int*)d_in[28];
  const int*   dst       = (const int*)d_in[29];
  const int*   gid       = (const int*)d_in[30];

  char* ws = (char*)d_ws;
  size_t off = 0;
  auto take = [&](size_t bytes) -> char* {
    char* pp = ws + off;
    off += (bytes + 255) & ~(size_t)255;
    return pp;
  };
  int*      cnt      = (int*)take((size_t)N_FACES * 4);
  int*      fill     = (int*)take((size_t)N_FACES * 4);
  int*      row_ptr  = (int*)take((size_t)(N_FACES + 1) * 4);
  int*      bsum     = (int*)take((size_t)SCAN_NB * 4);
  int*      csr_src  = (int*)take((size_t)N_EDGES * 4);
  float*    csr_xe   = (float*)take((size_t)N_EDGES * 6 * 4);
  float2*   csr_stat = (float2*)take((size_t)N_EDGES * 8);
  unsigned* gmax_u   = (unsigned*)take(64);
  float*    gs       = (float*)take(64);
  float*    praw     = (float*)take((size_t)NB * HID * 4);
  float*    el       = (float*)take((size_t)N_FACES * 4 * 4);
  float*    er       = (float*)take((size_t)N_FACES * 4 * 4);
  float*    gate     = (float*)take((size_t)N_FACES * 4);
  float*    f        = (float*)take((size_t)N_FACES * HID * 4);

  float* outp   = (float*)d_out;
  float* feat   = outp;
  float* h      = outp + NB * NOUT;
  float* pooled = outp + NB * NOUT + (size_t)N_FACES * HID;

  hipMemsetAsync(cnt, 0, (size_t)N_FACES * 4, stream);
  hipMemsetAsync(fill, 0, (size_t)N_FACES * 4, stream);
  hipMemsetAsync(gmax_u, 0, 64, stream);
  hipMemsetAsync(gs, 0, 64, stream);
  hipMemsetAsync(praw, 0, (size_t)NB * HID * 4, stream);

  k_hist<<<(N_EDGES + 255) / 256, 256, 0, stream>>>(dst, cnt);
  k_scan1<<<SCAN_NB, SCAN_B, 0, stream>>>(cnt, bsum);
  k_scan2<<<1, 64, 0, stream>>>(bsum);
  k_scan3<<<SCAN_NB, SCAN_B, 0, stream>>>(cnt, bsum, row_ptr);
  k_scatter<<<(N_EDGES + 255) / 256, 256, 0, stream>>>(dst, src, x_edge, row_ptr,
                                                       edge_W, edge_b, fill,
                                                       csr_xe, csr_src, csr_stat);

  k_encode<<<N_FACES / 4, 256, 0, stream>>>(x_face, csr_xe, face_W, face_b, face_g, face_beta,
                                            edge_W, edge_b, edge_g, edge_beta,
                                            row_ptr, csr_stat, h);
  // GAT layer 0
  k_gemm_elr<<<N_FACES / GM, 256, 0, stream>>>(h, g0_W, g0_al, g0_ar, f, el, er);
  k_gat<<<N_FACES / 4, 256, 0, stream>>>(f, el, er, row_ptr, csr_src,
                                         g0_bias, g0_g, g0_beta, h);
  // GAT layer 1
  k_gemm_elr<<<N_FACES / GM, 256, 0, stream>>>(h, g1_W, g1_al, g1_ar, f, el, er);
  k_gat<<<N_FACES / 4, 256, 0, stream>>>(f, el, er, row_ptr, csr_src,
                                         g1_bias, g1_g, g1_beta, h);
  // pooling + output head
  k_gate<<<N_FACES / 4, 256, 0, stream>>>(h, gate_W, gate_b, gate);
  k_gmax<<<(N_FACES + 255) / 256, 256, 0, stream>>>(gate, gid, gmax_u);
  k_psum<<<(N_FACES + PCHUNK - 1) / PCHUNK, 256, 0, stream>>>(h, gate, gid, gmax_u, praw, gs);
  k_poolnorm<<<NB, HID, 0, stream>>>(praw, gs, pooled);
  k_out<<<NB, NOUT, 0, stream>>>(pooled, out_W, out_b, out_g, out_beta, feat);
}

// Round 6
// 805.521 us; speedup vs baseline: 1.1232x; 1.1232x over previous
//
#include <hip/hip_runtime.h>

#define N_FACES 50000
#define N_EDGES 800000
#define NB      16
#define HID     256
#define NOUT    512
#define SCAN_B  1024
#define SCAN_NB ((N_FACES + SCAN_B - 1) / SCAN_B)

// ---------- wave helpers ----------
__device__ __forceinline__ float wave_sum(float v) {
#pragma unroll
  for (int o = 32; o; o >>= 1) v += __shfl_xor(v, o, 64);
  return v;
}

// ---------- order-preserving float<->uint encoding (for atomicMax) ----------
__device__ __forceinline__ unsigned enc_ord(float v) {
  unsigned b = __float_as_uint(v);
  return (b & 0x80000000u) ? ~b : (b | 0x80000000u);
}
__device__ __forceinline__ float dec_ord(unsigned e) {
  unsigned b = (e & 0x80000000u) ? (e ^ 0x80000000u) : ~e;
  return __uint_as_float(b);
}

// ---------- CSR build ----------
__global__ void k_hist(const int* __restrict__ dst, int* __restrict__ cnt) {
  int e = blockIdx.x * blockDim.x + threadIdx.x;
  if (e < N_EDGES) atomicAdd(&cnt[dst[e]], 1);
}

// 3-phase parallel exclusive scan of cnt[N_FACES] -> row_ptr[N_FACES+1]
__global__ void k_scan1(const int* __restrict__ cnt, int* __restrict__ bsum) {
  __shared__ int sh[SCAN_B];
  int i = blockIdx.x * SCAN_B + threadIdx.x;
  sh[threadIdx.x] = (i < N_FACES) ? cnt[i] : 0;
  __syncthreads();
  for (int off = SCAN_B / 2; off; off >>= 1) {
    if (threadIdx.x < off) sh[threadIdx.x] += sh[threadIdx.x + off];
    __syncthreads();
  }
  if (threadIdx.x == 0) bsum[blockIdx.x] = sh[0];
}

__global__ void k_scan2(int* __restrict__ bsum) {  // nb <= 64, one wave
  int t = threadIdx.x;
  int v = (t < SCAN_NB) ? bsum[t] : 0;
  int inc = v;
#pragma unroll
  for (int off = 1; off < 64; off <<= 1) {
    int u = __shfl_up(inc, off, 64);
    if (t >= off) inc += u;
  }
  if (t < SCAN_NB) bsum[t] = inc - v;  // exclusive
}

__global__ void k_scan3(const int* __restrict__ cnt, const int* __restrict__ bsum,
                        int* __restrict__ row_ptr) {
  __shared__ int sh[SCAN_B];
  int i = blockIdx.x * SCAN_B + threadIdx.x;
  int v = (i < N_FACES) ? cnt[i] : 0;
  sh[threadIdx.x] = v;
  __syncthreads();
  for (int off = 1; off < SCAN_B; off <<= 1) {
    int x = (threadIdx.x >= off) ? sh[threadIdx.x - off] : 0;
    __syncthreads();
    sh[threadIdx.x] += x;
    __syncthreads();
  }
  if (i < N_FACES) row_ptr[i] = bsum[blockIdx.x] + sh[threadIdx.x] - v;
  if (i == 0) row_ptr[N_FACES] = N_EDGES;
}

// scatter edge features + src ids into CSR order AND compute per-edge LN stats
__global__ void k_scatter(const int* __restrict__ dst, const int* __restrict__ src,
                          const float* __restrict__ xe, const int* __restrict__ row_ptr,
                          const float* __restrict__ eW, const float* __restrict__ eB,
                          int* __restrict__ fill, float* __restrict__ csr_xe,
                          int* __restrict__ csr_src, float2* __restrict__ csr_stat) {
  __shared__ float sw[6][HID];
  __shared__ float sb[HID];
  int t0 = threadIdx.x;
  for (int i = t0; i < 6 * HID; i += 256) sw[i / HID][i % HID] = eW[i];
  for (int i = t0; i < HID; i += 256) sb[i] = eB[i];
  __syncthreads();

  int e = blockIdx.x * blockDim.x + t0;
  if (e >= N_EDGES) return;
  float z[6];
#pragma unroll
  for (int k = 0; k < 6; ++k) z[k] = xe[(size_t)e * 6 + k];
  int d = dst[e];
  int p = atomicAdd(&fill[d], 1);
  int pos = row_ptr[d] + p;
  csr_src[pos] = src[e];
#pragma unroll
  for (int k = 0; k < 6; ++k) csr_xe[(size_t)pos * 6 + k] = z[k];

  float s1 = 0.f, s2 = 0.f;
  for (int c = 0; c < HID; c += 4) {
    float4 w4 = *reinterpret_cast<const float4*>(&sb[c]);
#pragma unroll
    for (int k = 0; k < 6; ++k) {
      float4 m4 = *reinterpret_cast<const float4*>(&sw[k][c]);
      w4.x += z[k] * m4.x; w4.y += z[k] * m4.y;
      w4.z += z[k] * m4.z; w4.w += z[k] * m4.w;
    }
    w4.x = fmaxf(w4.x, 0.f); w4.y = fmaxf(w4.y, 0.f);
    w4.z = fmaxf(w4.z, 0.f); w4.w = fmaxf(w4.w, 0.f);
    s1 += (w4.x + w4.y) + (w4.z + w4.w);
    s2 += (w4.x * w4.x + w4.y * w4.y) + (w4.z * w4.z + w4.w * w4.w);
  }
  float mu = s1 * (1.f / HID);
  float rs = rsqrtf(fmaxf(s2 * (1.f / HID) - mu * mu, 0.f) + 1e-5f);
  csr_stat[pos] = make_float2(mu, rs);
}

// ---------- encoders + mean aggregation (one wave per node, no shuffles in edge loop) ----------
__global__ void k_encode(const float* __restrict__ xf, const float* __restrict__ csr_xe,
                         const float* __restrict__ fW, const float* __restrict__ fB,
                         const float* __restrict__ fG, const float* __restrict__ fBe,
                         const float* __restrict__ eW, const float* __restrict__ eB,
                         const float* __restrict__ eG, const float* __restrict__ eBe,
                         const int* __restrict__ row_ptr, const float2* __restrict__ csr_stat,
                         float* __restrict__ h) {
  int lane = threadIdx.x & 63;
  int n = blockIdx.x * 4 + (threadIdx.x >> 6);
  if (n >= N_FACES) return;

  // face encoder
  float x[7];
#pragma unroll
  for (int k = 0; k < 7; ++k) x[k] = xf[n * 7 + k];
  float y[4];
#pragma unroll
  for (int j = 0; j < 4; ++j) {
    int c = lane + 64 * j;
    float a = fB[c];
#pragma unroll
    for (int k = 0; k < 7; ++k) a += x[k] * fW[k * HID + c];
    y[j] = fmaxf(a, 0.f);
  }
  float s = y[0] + y[1] + y[2] + y[3];
  float s2 = y[0] * y[0] + y[1] * y[1] + y[2] * y[2] + y[3] * y[3];
  s = wave_sum(s); s2 = wave_sum(s2);
  float mu = s * (1.f / HID);
  float rs = rsqrtf(fmaxf(s2 * (1.f / HID) - mu * mu, 0.f) + 1e-5f);
  float hv[4];
#pragma unroll
  for (int j = 0; j < 4; ++j) {
    int c = lane + 64 * j;
    hv[j] = (y[j] - mu) * rs * fG[c] + fBe[c];
  }

  // hoist edge-encoder params into registers (loop-invariant)
  float ew[6][4], eb[4], eg[4], ebe[4];
#pragma unroll
  for (int j = 0; j < 4; ++j) {
    int c = lane + 64 * j;
    eb[j] = eB[c]; eg[j] = eG[c]; ebe[j] = eBe[c];
#pragma unroll
    for (int k = 0; k < 6; ++k) ew[k][j] = eW[k * HID + c];
  }

  int e0 = row_ptr[n], e1 = row_ptr[n + 1];
  float acc[4] = {0.f, 0.f, 0.f, 0.f};
  for (int t = e0; t < e1; ++t) {
    float2 st = csr_stat[t];
    float z[6];
#pragma unroll
    for (int k = 0; k < 6; ++k) z[k] = csr_xe[(size_t)t * 6 + k];
#pragma unroll
    for (int j = 0; j < 4; ++j) {
      float a = eb[j];
#pragma unroll
      for (int k = 0; k < 6; ++k) a += z[k] * ew[k][j];
      a = fmaxf(a, 0.f);
      acc[j] += (a - st.x) * (st.y * eg[j]) + ebe[j];
    }
  }
  float inv = (e1 > e0) ? 1.f / (float)(e1 - e0) : 0.f;
#pragma unroll
  for (int j = 0; j < 4; ++j) h[(size_t)n * HID + lane + 64 * j] = hv[j] + acc[j] * inv;
}

// ---------- f = h @ W with fused el/er (32 nodes/block; FMA-dominated issue mix) ----------
// 256 threads: q = tid&63 -> cols 4q..4q+3 (float4); wave wv = tid>>6 -> nodes wv*8..wv*8+7
#define GM 32
__global__ void k_gemm_elr(const float* __restrict__ h, const float* __restrict__ W,
                           const float* __restrict__ al, const float* __restrict__ ar,
                           float* __restrict__ f, float* __restrict__ el,
                           float* __restrict__ er) {
  __shared__ float hs[GM][HID];
  int n0 = blockIdx.x * GM;
  int tid = threadIdx.x;
  int q = tid & 63;
  int wv = tid >> 6;

  // stage h tile (guarded for tail block)
  {
    const float4* hsrc = reinterpret_cast<const float4*>(h);
    float4* hdst = reinterpret_cast<float4*>(&hs[0][0]);
    for (int i = tid; i < GM * HID / 4; i += 256) {
      int n = n0 + (i >> 6);
      hdst[i] = (n < N_FACES) ? hsrc[(size_t)n0 * 64 + i] : make_float4(0.f, 0.f, 0.f, 0.f);
    }
  }
  __syncthreads();

  float4 acc[8];
#pragma unroll
  for (int m = 0; m < 8; ++m) acc[m] = make_float4(0.f, 0.f, 0.f, 0.f);

  const float* Wq = W + 4 * q;
  for (int k = 0; k < HID; k += 4) {
    float4 w0 = *reinterpret_cast<const float4*>(Wq + (size_t)(k + 0) * HID);
    float4 w1 = *reinterpret_cast<const float4*>(Wq + (size_t)(k + 1) * HID);
    float4 w2 = *reinterpret_cast<const float4*>(Wq + (size_t)(k + 2) * HID);
    float4 w3 = *reinterpret_cast<const float4*>(Wq + (size_t)(k + 3) * HID);
#pragma unroll
    for (int m = 0; m < 8; ++m) {
      float4 h4 = *reinterpret_cast<const float4*>(&hs[wv * 8 + m][k]);
      acc[m].x = fmaf(h4.x, w0.x, acc[m].x); acc[m].y = fmaf(h4.x, w0.y, acc[m].y);
      acc[m].z = fmaf(h4.x, w0.z, acc[m].z); acc[m].w = fmaf(h4.x, w0.w, acc[m].w);
      acc[m].x = fmaf(h4.y, w1.x, acc[m].x); acc[m].y = fmaf(h4.y, w1.y, acc[m].y);
      acc[m].z = fmaf(h4.y, w1.z, acc[m].z); acc[m].w = fmaf(h4.y, w1.w, acc[m].w);
      acc[m].x = fmaf(h4.z, w2.x, acc[m].x); acc[m].y = fmaf(h4.z, w2.y, acc[m].y);
      acc[m].z = fmaf(h4.z, w2.z, acc[m].z); acc[m].w = fmaf(h4.z, w2.w, acc[m].w);
      acc[m].x = fmaf(h4.w, w3.x, acc[m].x); acc[m].y = fmaf(h4.w, w3.y, acc[m].y);
      acc[m].z = fmaf(h4.w, w3.z, acc[m].z); acc[m].w = fmaf(h4.w, w3.w, acc[m].w);
    }
  }

  // epilogue: store f, compute el/er via 16-lane segmented reduce (head = q>>4)
  int hd = q >> 4;
  float4 alv = *reinterpret_cast<const float4*>(al + 4 * q);
  float4 arv = *reinterpret_cast<const float4*>(ar + 4 * q);
#pragma unroll
  for (int m = 0; m < 8; ++m) {
    int n = n0 + wv * 8 + m;
    if (n >= N_FACES) break;
    *reinterpret_cast<float4*>(f + (size_t)n * HID + 4 * q) = acc[m];
    float pl = acc[m].x * alv.x + acc[m].y * alv.y + acc[m].z * alv.z + acc[m].w * alv.w;
    float pr = acc[m].x * arv.x + acc[m].y * arv.y + acc[m].z * arv.z + acc[m].w * arv.w;
#pragma unroll
    for (int o = 1; o < 16; o <<= 1) {
      pl += __shfl_xor(pl, o, 64);
      pr += __shfl_xor(pr, o, 64);
    }
    if ((q & 15) == 0) {
      el[n * 4 + hd] = pl;
      er[n * 4 + hd] = pr;
    }
  }
}

// ---------- GAT: single fused edge pass, 1-ahead software prefetch ----------
__global__ void k_gat(const float* __restrict__ f, const float* __restrict__ el,
                      const float* __restrict__ er, const int* __restrict__ row_ptr,
                      const int* __restrict__ csrc,
                      const float* __restrict__ bias, const float* __restrict__ g,
                      const float* __restrict__ be, float* __restrict__ h) {
  int lane = threadIdx.x & 63;
  int n = blockIdx.x * 4 + (threadIdx.x >> 6);
  if (n >= N_FACES) return;
  int e0 = row_ptr[n], e1 = row_ptr[n + 1];
  float4 ern = reinterpret_cast<const float4*>(er)[n];

  float s0 = 0.f, s1 = 0.f, s2 = 0.f, s3 = 0.f;
  float a0 = 0.f, a1 = 0.f, a2 = 0.f, a3 = 0.f;
  if (e0 < e1) {
    int sp = csrc[e0];
    float4 ep = reinterpret_cast<const float4*>(el)[sp];
    const float* fr = f + (size_t)sp * HID;
    float f0 = fr[lane], f1 = fr[lane + 64], f2 = fr[lane + 128], f3 = fr[lane + 192];
    for (int t = e0; t < e1; ++t) {
      int sn = 0; float4 en = ep;
      float g0 = 0.f, g1 = 0.f, g2 = 0.f, g3 = 0.f;
      if (t + 1 < e1) {
        sn = csrc[t + 1];
        en = reinterpret_cast<const float4*>(el)[sn];
        const float* frn = f + (size_t)sn * HID;
        g0 = frn[lane]; g1 = frn[lane + 64]; g2 = frn[lane + 128]; g3 = frn[lane + 192];
      }
      float w, p;
      w = ep.x + ern.x; w = fmaxf(w, 0.2f * w); p = __expf(w); s0 += p; a0 += f0 * p;
      w = ep.y + ern.y; w = fmaxf(w, 0.2f * w); p = __expf(w); s1 += p; a1 += f1 * p;
      w = ep.z + ern.z; w = fmaxf(w, 0.2f * w); p = __expf(w); s2 += p; a2 += f2 * p;
      w = ep.w + ern.w; w = fmaxf(w, 0.2f * w); p = __expf(w); s3 += p; a3 += f3 * p;
      ep = en; f0 = g0; f1 = g1; f2 = g2; f3 = g3;
    }
  }
  a0 *= (s0 > 0.f ? 1.f / s0 : 0.f);
  a1 *= (s1 > 0.f ? 1.f / s1 : 0.f);
  a2 *= (s2 > 0.f ? 1.f / s2 : 0.f);
  a3 *= (s3 > 0.f ? 1.f / s3 : 0.f);

  float y0 = fmaxf(a0 + bias[lane], 0.f);
  float y1 = fmaxf(a1 + bias[lane + 64], 0.f);
  float y2 = fmaxf(a2 + bias[lane + 128], 0.f);
  float y3 = fmaxf(a3 + bias[lane + 192], 0.f);
  float s = y0 + y1 + y2 + y3;
  float q = y0 * y0 + y1 * y1 + y2 * y2 + y3 * y3;
  s = wave_sum(s); q = wave_sum(q);
  float mu = s * (1.f / HID);
  float rs = rsqrtf(fmaxf(q * (1.f / HID) - mu * mu, 0.f) + 1e-5f);
  size_t base = (size_t)n * HID;
  h[base + lane]       = (y0 - mu) * rs * g[lane]       + be[lane];
  h[base + lane + 64]  = (y1 - mu) * rs * g[lane + 64]  + be[lane + 64];
  h[base + lane + 128] = (y2 - mu) * rs * g[lane + 128] + be[lane + 128];
  h[base + lane + 192] = (y3 - mu) * rs * g[lane + 192] + be[lane + 192];
}

// ---------- gate scores ----------
__global__ void k_gate(const float* __restrict__ h, const float* __restrict__ gw,
                       const float* __restrict__ gb, float* __restrict__ gate) {
  int lane = threadIdx.x & 63;
  int n = blockIdx.x * 4 + (threadIdx.x >> 6);
  if (n >= N_FACES) return;
  float4 v = reinterpret_cast<const float4*>(h)[(size_t)n * 64 + lane];
  float4 w = reinterpret_cast<const float4*>(gw)[lane];
  float p = v.x * w.x + v.y * w.y + v.z * w.z + v.w * w.w;
  p = wave_sum(p);
  if (lane == 0) gate[n] = p + gb[0];
}

// ---------- per-graph max of gate: LDS pre-reduction, then global atomics ----------
__global__ void k_gmax(const float* __restrict__ gate, const int* __restrict__ gid,
                       unsigned* __restrict__ gmax_u) {
  __shared__ unsigned sm[NB];
  int t = threadIdx.x;
  if (t < NB) sm[t] = 0u;
  __syncthreads();
  int n = blockIdx.x * blockDim.x + t;
  if (n < N_FACES) atomicMax(&sm[gid[n]], enc_ord(gate[n]));
  __syncthreads();
  if (t < NB && sm[t] != 0u) atomicMax(&gmax_u[t], sm[t]);
}

// ---------- parallel weighted pooling (unnormalized) ----------
#define PCHUNK 125
__global__ void k_psum(const float* __restrict__ h, const float* __restrict__ gate,
                       const int* __restrict__ gid, const unsigned* __restrict__ gmax_u,
                       float* __restrict__ praw, float* __restrict__ gs) {
  int t = threadIdx.x;
  int n0 = blockIdx.x * PCHUNK;
  int n1 = n0 + PCHUNK;
  if (n1 > N_FACES) n1 = N_FACES;
  if (n0 >= N_FACES) return;
  int cur = gid[n0];
  float gm = dec_ord(gmax_u[cur]);
  float acc = 0.f, wsum = 0.f;
  for (int n = n0; n < n1; ++n) {
    int g = gid[n];
    if (g != cur) {
      atomicAdd(&praw[cur * HID + t], acc);
      if (t == 0) atomicAdd(&gs[cur], wsum);
      acc = 0.f; wsum = 0.f; cur = g; gm = dec_ord(gmax_u[cur]);
    }
    float w = __expf(gate[n] - gm);
    acc += w * h[(size_t)n * HID + t];
    wsum += w;
  }
  atomicAdd(&praw[cur * HID + t], acc);
  if (t == 0) atomicAdd(&gs[cur], wsum);
}

__global__ void k_poolnorm(const float* __restrict__ praw, const float* __restrict__ gs,
                           float* __restrict__ pooled) {
  int b = blockIdx.x, c = threadIdx.x;
  pooled[b * HID + c] = praw[b * HID + c] / gs[b];
}

// ---------- output projection + LN ----------
__global__ void k_out(const float* __restrict__ pooled, const float* __restrict__ oW,
                      const float* __restrict__ oB, const float* __restrict__ oG,
                      const float* __restrict__ oBe, float* __restrict__ feat) {
  int b = blockIdx.x;
  int o = threadIdx.x;  // 512 threads
  int lane = o & 63, wid = o >> 6;
  __shared__ float p[HID];
  __shared__ float partS[8], partQ[8];
  __shared__ float shMu, shRs;
  if (o < HID) p[o] = pooled[b * HID + o];
  __syncthreads();
  float a = oB[o];
  for (int k = 0; k < HID; ++k) a += p[k] * oW[k * NOUT + o];
  float y = fmaxf(a, 0.f);
  float s = wave_sum(y), q = wave_sum(y * y);
  if (lane == 0) { partS[wid] = s; partQ[wid] = q; }
  __syncthreads();
  if (o == 0) {
    float S = 0.f, Q = 0.f;
#pragma unroll
    for (int i = 0; i < 8; ++i) { S += partS[i]; Q += partQ[i]; }
    float mu = S * (1.f / NOUT);
    shMu = mu;
    shRs = rsqrtf(fmaxf(Q * (1.f / NOUT) - mu * mu, 0.f) + 1e-5f);
  }
  __syncthreads();
  feat[b * NOUT + o] = (y - shMu) * shRs * oG[o] + oBe[o];
}

extern "C" void kernel_launch(void* const* d_in, const int* in_sizes, int n_in,
                              void* d_out, int out_size, void* d_ws, size_t ws_size,
                              hipStream_t stream) {
  (void)in_sizes; (void)n_in; (void)out_size; (void)ws_size;
  const float* x_face    = (const float*)d_in[0];
  const float* x_edge    = (const float*)d_in[1];
  const float* face_W    = (const float*)d_in[2];
  const float* face_b    = (const float*)d_in[3];
  const float* face_g    = (const float*)d_in[4];
  const float* face_beta = (const float*)d_in[5];
  const float* edge_W    = (const float*)d_in[6];
  const float* edge_b    = (const float*)d_in[7];
  const float* edge_g    = (const float*)d_in[8];
  const float* edge_beta = (const float*)d_in[9];
  const float* g0_W      = (const float*)d_in[10];
  const float* g0_al     = (const float*)d_in[11];
  const float* g0_ar     = (const float*)d_in[12];
  const float* g0_bias   = (const float*)d_in[13];
  const float* g0_g      = (const float*)d_in[14];
  const float* g0_beta   = (const float*)d_in[15];
  const float* g1_W      = (const float*)d_in[16];
  const float* g1_al     = (const float*)d_in[17];
  const float* g1_ar     = (const float*)d_in[18];
  const float* g1_bias   = (const float*)d_in[19];
  const float* g1_g      = (const float*)d_in[20];
  const float* g1_beta   = (const float*)d_in[21];
  const float* gate_W    = (const float*)d_in[22];
  const float* gate_b    = (const float*)d_in[23];
  const float* out_W     = (const float*)d_in[24];
  const float* out_b     = (const float*)d_in[25];
  const float* out_g     = (const float*)d_in[26];
  const float* out_beta  = (const float*)d_in[27];
  const int*   src       = (const int*)d_in[28];
  const int*   dst       = (const int*)d_in[29];
  const int*   gid       = (const int*)d_in[30];

  char* ws = (char*)d_ws;
  size_t off = 0;
  auto take = [&](size_t bytes) -> char* {
    char* pp = ws + off;
    off += (bytes + 255) & ~(size_t)255;
    return pp;
  };
  int*      cnt      = (int*)take((size_t)N_FACES * 4);
  int*      fill     = (int*)take((size_t)N_FACES * 4);
  int*      row_ptr  = (int*)take((size_t)(N_FACES + 1) * 4);
  int*      bsum     = (int*)take((size_t)SCAN_NB * 4);
  int*      csr_src  = (int*)take((size_t)N_EDGES * 4);
  float*    csr_xe   = (float*)take((size_t)N_EDGES * 6 * 4);
  float2*   csr_stat = (float2*)take((size_t)N_EDGES * 8);
  unsigned* gmax_u   = (unsigned*)take(64);
  float*    gs       = (float*)take(64);
  float*    praw     = (float*)take((size_t)NB * HID * 4);
  float*    el       = (float*)take((size_t)N_FACES * 4 * 4);
  float*    er       = (float*)take((size_t)N_FACES * 4 * 4);
  float*    gate     = (float*)take((size_t)N_FACES * 4);
  float*    f        = (float*)take((size_t)N_FACES * HID * 4);

  float* outp   = (float*)d_out;
  float* feat   = outp;
  float* h      = outp + NB * NOUT;
  float* pooled = outp + NB * NOUT + (size_t)N_FACES * HID;

  hipMemsetAsync(cnt, 0, (size_t)N_FACES * 4, stream);
  hipMemsetAsync(fill, 0, (size_t)N_FACES * 4, stream);
  hipMemsetAsync(gmax_u, 0, 64, stream);
  hipMemsetAsync(gs, 0, 64, stream);
  hipMemsetAsync(praw, 0, (size_t)NB * HID * 4, stream);

  k_hist<<<(N_EDGES + 255) / 256, 256, 0, stream>>>(dst, cnt);
  k_scan1<<<SCAN_NB, SCAN_B, 0, stream>>>(cnt, bsum);
  k_scan2<<<1, 64, 0, stream>>>(bsum);
  k_scan3<<<SCAN_NB, SCAN_B, 0, stream>>>(cnt, bsum, row_ptr);
  k_scatter<<<(N_EDGES + 255) / 256, 256, 0, stream>>>(dst, src, x_edge, row_ptr,
                                                       edge_W, edge_b, fill,
                                                       csr_xe, csr_src, csr_stat);

  k_encode<<<N_FACES / 4, 256, 0, stream>>>(x_face, csr_xe, face_W, face_b, face_g, face_beta,
                                            edge_W, edge_b, edge_g, edge_beta,
                                            row_ptr, csr_stat, h);
  // GAT layer 0
  k_gemm_elr<<<(N_FACES + GM - 1) / GM, 256, 0, stream>>>(h, g0_W, g0_al, g0_ar, f, el, er);
  k_gat<<<N_FACES / 4, 256, 0, stream>>>(f, el, er, row_ptr, csr_src,
                                         g0_bias, g0_g, g0_beta, h);
  // GAT layer 1
  k_gemm_elr<<<(N_FACES + GM - 1) / GM, 256, 0, stream>>>(h, g1_W, g1_al, g1_ar, f, el, er);
  k_gat<<<N_FACES / 4, 256, 0, stream>>>(f, el, er, row_ptr, csr_src,
                                         g1_bias, g1_g, g1_beta, h);
  // pooling + output head
  k_gate<<<N_FACES / 4, 256, 0, stream>>>(h, gate_W, gate_b, gate);
  k_gmax<<<(N_FACES + 255) / 256, 256, 0, stream>>>(gate, gid, gmax_u);
  k_psum<<<(N_FACES + PCHUNK - 1) / PCHUNK, 256, 0, stream>>>(h, gate, gid, gmax_u, praw, gs);
  k_poolnorm<<<NB, HID, 0, stream>>>(praw, gs, pooled);
  k_out<<<NB, NOUT, 0, stream>>>(pooled, out_W, out_b, out_g, out_beta, feat);
}

// Round 7
// 760.427 us; speedup vs baseline: 1.1898x; 1.0593x over previous
//
#include <hip/hip_runtime.h>

#define N_FACES 50000
#define N_EDGES 800000
#define NB      16
#define HID     256
#define NOUT    512
#define SCAN_B  1024
#define SCAN_NB ((N_FACES + SCAN_B - 1) / SCAN_B)

// ---------- wave helpers ----------
__device__ __forceinline__ float wave_sum(float v) {
#pragma unroll
  for (int o = 32; o; o >>= 1) v += __shfl_xor(v, o, 64);
  return v;
}

// ---------- order-preserving float<->uint encoding (for atomicMax) ----------
__device__ __forceinline__ unsigned enc_ord(float v) {
  unsigned b = __float_as_uint(v);
  return (b & 0x80000000u) ? ~b : (b | 0x80000000u);
}
__device__ __forceinline__ float dec_ord(unsigned e) {
  unsigned b = (e & 0x80000000u) ? (e ^ 0x80000000u) : ~e;
  return __uint_as_float(b);
}

// ---------- CSR build ----------
__global__ void k_hist(const int* __restrict__ dst, int* __restrict__ cnt) {
  int e = blockIdx.x * blockDim.x + threadIdx.x;
  if (e < N_EDGES) atomicAdd(&cnt[dst[e]], 1);
}

// 3-phase parallel exclusive scan of cnt[N_FACES] -> row_ptr[N_FACES+1]
__global__ void k_scan1(const int* __restrict__ cnt, int* __restrict__ bsum) {
  __shared__ int sh[SCAN_B];
  int i = blockIdx.x * SCAN_B + threadIdx.x;
  sh[threadIdx.x] = (i < N_FACES) ? cnt[i] : 0;
  __syncthreads();
  for (int off = SCAN_B / 2; off; off >>= 1) {
    if (threadIdx.x < off) sh[threadIdx.x] += sh[threadIdx.x + off];
    __syncthreads();
  }
  if (threadIdx.x == 0) bsum[blockIdx.x] = sh[0];
}

__global__ void k_scan2(int* __restrict__ bsum) {  // nb <= 64, one wave
  int t = threadIdx.x;
  int v = (t < SCAN_NB) ? bsum[t] : 0;
  int inc = v;
#pragma unroll
  for (int off = 1; off < 64; off <<= 1) {
    int u = __shfl_up(inc, off, 64);
    if (t >= off) inc += u;
  }
  if (t < SCAN_NB) bsum[t] = inc - v;  // exclusive
}

__global__ void k_scan3(const int* __restrict__ cnt, const int* __restrict__ bsum,
                        int* __restrict__ row_ptr) {
  __shared__ int sh[SCAN_B];
  int i = blockIdx.x * SCAN_B + threadIdx.x;
  int v = (i < N_FACES) ? cnt[i] : 0;
  sh[threadIdx.x] = v;
  __syncthreads();
  for (int off = 1; off < SCAN_B; off <<= 1) {
    int x = (threadIdx.x >= off) ? sh[threadIdx.x - off] : 0;
    __syncthreads();
    sh[threadIdx.x] += x;
    __syncthreads();
  }
  if (i < N_FACES) row_ptr[i] = bsum[blockIdx.x] + sh[threadIdx.x] - v;
  if (i == 0) row_ptr[N_FACES] = N_EDGES;
}

// scatter edge {features, LN stats} as one 32B record into CSR order
__global__ void k_scatter(const int* __restrict__ dst, const int* __restrict__ src,
                          const float* __restrict__ xe, const int* __restrict__ row_ptr,
                          const float* __restrict__ eW, const float* __restrict__ eB,
                          int* __restrict__ fill, float* __restrict__ csr_rec,
                          int* __restrict__ csr_src) {
  __shared__ float sw[6][HID];
  __shared__ float sb[HID];
  int t0 = threadIdx.x;
  for (int i = t0; i < 6 * HID; i += 256) sw[i / HID][i % HID] = eW[i];
  for (int i = t0; i < HID; i += 256) sb[i] = eB[i];
  __syncthreads();

  int e = blockIdx.x * blockDim.x + t0;
  if (e >= N_EDGES) return;
  float z[6];
#pragma unroll
  for (int k = 0; k < 6; ++k) z[k] = xe[(size_t)e * 6 + k];
  int d = dst[e];
  int p = atomicAdd(&fill[d], 1);
  int pos = row_ptr[d] + p;
  csr_src[pos] = src[e];

  float s1 = 0.f, s2 = 0.f;
  for (int c = 0; c < HID; c += 4) {
    float4 w4 = *reinterpret_cast<const float4*>(&sb[c]);
#pragma unroll
    for (int k = 0; k < 6; ++k) {
      float4 m4 = *reinterpret_cast<const float4*>(&sw[k][c]);
      w4.x += z[k] * m4.x; w4.y += z[k] * m4.y;
      w4.z += z[k] * m4.z; w4.w += z[k] * m4.w;
    }
    w4.x = fmaxf(w4.x, 0.f); w4.y = fmaxf(w4.y, 0.f);
    w4.z = fmaxf(w4.z, 0.f); w4.w = fmaxf(w4.w, 0.f);
    s1 += (w4.x + w4.y) + (w4.z + w4.w);
    s2 += (w4.x * w4.x + w4.y * w4.y) + (w4.z * w4.z + w4.w * w4.w);
  }
  float mu = s1 * (1.f / HID);
  float rs = rsqrtf(fmaxf(s2 * (1.f / HID) - mu * mu, 0.f) + 1e-5f);
  float4* out = reinterpret_cast<float4*>(csr_rec);
  out[(size_t)pos * 2]     = make_float4(z[0], z[1], z[2], z[3]);
  out[(size_t)pos * 2 + 1] = make_float4(z[4], z[5], mu, rs);
}

// ---------- encoders + mean aggregation (one wave per node; 2 vec loads/edge, prefetched) ----------
__global__ void k_encode(const float* __restrict__ xf, const float* __restrict__ csr_rec,
                         const float* __restrict__ fW, const float* __restrict__ fB,
                         const float* __restrict__ fG, const float* __restrict__ fBe,
                         const float* __restrict__ eW, const float* __restrict__ eB,
                         const float* __restrict__ eG, const float* __restrict__ eBe,
                         const int* __restrict__ row_ptr, float* __restrict__ h) {
  int lane = threadIdx.x & 63;
  int n = blockIdx.x * 4 + (threadIdx.x >> 6);
  if (n >= N_FACES) return;

  // face encoder
  float x[7];
#pragma unroll
  for (int k = 0; k < 7; ++k) x[k] = xf[n * 7 + k];
  float y[4];
#pragma unroll
  for (int j = 0; j < 4; ++j) {
    int c = lane + 64 * j;
    float a = fB[c];
#pragma unroll
    for (int k = 0; k < 7; ++k) a += x[k] * fW[k * HID + c];
    y[j] = fmaxf(a, 0.f);
  }
  float s = y[0] + y[1] + y[2] + y[3];
  float s2 = y[0] * y[0] + y[1] * y[1] + y[2] * y[2] + y[3] * y[3];
  s = wave_sum(s); s2 = wave_sum(s2);
  float mu = s * (1.f / HID);
  float rs = rsqrtf(fmaxf(s2 * (1.f / HID) - mu * mu, 0.f) + 1e-5f);
  float hv[4];
#pragma unroll
  for (int j = 0; j < 4; ++j) {
    int c = lane + 64 * j;
    hv[j] = (y[j] - mu) * rs * fG[c] + fBe[c];
  }

  // hoist edge-encoder params into registers (loop-invariant)
  float ew[6][4], eb[4], eg[4], ebe[4];
#pragma unroll
  for (int j = 0; j < 4; ++j) {
    int c = lane + 64 * j;
    eb[j] = eB[c]; eg[j] = eG[c]; ebe[j] = eBe[c];
#pragma unroll
    for (int k = 0; k < 6; ++k) ew[k][j] = eW[k * HID + c];
  }

  int e0 = row_ptr[n], e1 = row_ptr[n + 1];
  float acc[4] = {0.f, 0.f, 0.f, 0.f};
  const float4* rec = reinterpret_cast<const float4*>(csr_rec);
  float4 pa, pb;
  if (e0 < e1) {
    pa = rec[(size_t)e0 * 2];
    pb = rec[(size_t)e0 * 2 + 1];
  }
  for (int t = e0; t < e1; ++t) {
    float4 ca = pa, cb = pb;
    if (t + 1 < e1) {
      pa = rec[(size_t)(t + 1) * 2];
      pb = rec[(size_t)(t + 1) * 2 + 1];
    }
    float z0 = ca.x, z1 = ca.y, z2 = ca.z, z3 = ca.w, z4 = cb.x, z5 = cb.y;
    float emu = cb.z, ers = cb.w;
#pragma unroll
    for (int j = 0; j < 4; ++j) {
      float a = eb[j];
      a = fmaf(z0, ew[0][j], a); a = fmaf(z1, ew[1][j], a);
      a = fmaf(z2, ew[2][j], a); a = fmaf(z3, ew[3][j], a);
      a = fmaf(z4, ew[4][j], a); a = fmaf(z5, ew[5][j], a);
      a = fmaxf(a, 0.f);
      acc[j] += (a - emu) * (ers * eg[j]) + ebe[j];
    }
  }
  float inv = (e1 > e0) ? 1.f / (float)(e1 - e0) : 0.f;
#pragma unroll
  for (int j = 0; j < 4; ++j) h[(size_t)n * HID + lane + 64 * j] = hv[j] + acc[j] * inv;
}

// ---------- f = h @ W with fused el/er (32 nodes/block; FMA-dominated issue mix) ----------
#define GM 32
__global__ void k_gemm_elr(const float* __restrict__ h, const float* __restrict__ W,
                           const float* __restrict__ al, const float* __restrict__ ar,
                           float* __restrict__ f, float* __restrict__ el,
                           float* __restrict__ er) {
  __shared__ float hs[GM][HID];
  int n0 = blockIdx.x * GM;
  int tid = threadIdx.x;
  int q = tid & 63;
  int wv = tid >> 6;

  {
    const float4* hsrc = reinterpret_cast<const float4*>(h);
    float4* hdst = reinterpret_cast<float4*>(&hs[0][0]);
    for (int i = tid; i < GM * HID / 4; i += 256) {
      int n = n0 + (i >> 6);
      hdst[i] = (n < N_FACES) ? hsrc[(size_t)n0 * 64 + i] : make_float4(0.f, 0.f, 0.f, 0.f);
    }
  }
  __syncthreads();

  float4 acc[8];
#pragma unroll
  for (int m = 0; m < 8; ++m) acc[m] = make_float4(0.f, 0.f, 0.f, 0.f);

  const float* Wq = W + 4 * q;
  for (int k = 0; k < HID; k += 4) {
    float4 w0 = *reinterpret_cast<const float4*>(Wq + (size_t)(k + 0) * HID);
    float4 w1 = *reinterpret_cast<const float4*>(Wq + (size_t)(k + 1) * HID);
    float4 w2 = *reinterpret_cast<const float4*>(Wq + (size_t)(k + 2) * HID);
    float4 w3 = *reinterpret_cast<const float4*>(Wq + (size_t)(k + 3) * HID);
#pragma unroll
    for (int m = 0; m < 8; ++m) {
      float4 h4 = *reinterpret_cast<const float4*>(&hs[wv * 8 + m][k]);
      acc[m].x = fmaf(h4.x, w0.x, acc[m].x); acc[m].y = fmaf(h4.x, w0.y, acc[m].y);
      acc[m].z = fmaf(h4.x, w0.z, acc[m].z); acc[m].w = fmaf(h4.x, w0.w, acc[m].w);
      acc[m].x = fmaf(h4.y, w1.x, acc[m].x); acc[m].y = fmaf(h4.y, w1.y, acc[m].y);
      acc[m].z = fmaf(h4.y, w1.z, acc[m].z); acc[m].w = fmaf(h4.y, w1.w, acc[m].w);
      acc[m].x = fmaf(h4.z, w2.x, acc[m].x); acc[m].y = fmaf(h4.z, w2.y, acc[m].y);
      acc[m].z = fmaf(h4.z, w2.z, acc[m].z); acc[m].w = fmaf(h4.z, w2.w, acc[m].w);
      acc[m].x = fmaf(h4.w, w3.x, acc[m].x); acc[m].y = fmaf(h4.w, w3.y, acc[m].y);
      acc[m].z = fmaf(h4.w, w3.z, acc[m].z); acc[m].w = fmaf(h4.w, w3.w, acc[m].w);
    }
  }

  int hd = q >> 4;
  float4 alv = *reinterpret_cast<const float4*>(al + 4 * q);
  float4 arv = *reinterpret_cast<const float4*>(ar + 4 * q);
#pragma unroll
  for (int m = 0; m < 8; ++m) {
    int n = n0 + wv * 8 + m;
    if (n >= N_FACES) break;
    *reinterpret_cast<float4*>(f + (size_t)n * HID + 4 * q) = acc[m];
    float pl = acc[m].x * alv.x + acc[m].y * alv.y + acc[m].z * alv.z + acc[m].w * alv.w;
    float pr = acc[m].x * arv.x + acc[m].y * arv.y + acc[m].z * arv.z + acc[m].w * arv.w;
#pragma unroll
    for (int o = 1; o < 16; o <<= 1) {
      pl += __shfl_xor(pl, o, 64);
      pr += __shfl_xor(pr, o, 64);
    }
    if ((q & 15) == 0) {
      el[n * 4 + hd] = pl;
      er[n * 4 + hd] = pr;
    }
  }
}

// ---------- GAT: single fused edge pass, 1-ahead prefetch; optional fused gate ----------
__global__ void k_gat(const float* __restrict__ f, const float* __restrict__ el,
                      const float* __restrict__ er, const int* __restrict__ row_ptr,
                      const int* __restrict__ csrc,
                      const float* __restrict__ bias, const float* __restrict__ g,
                      const float* __restrict__ be, float* __restrict__ h,
                      const float* __restrict__ gw, const float* __restrict__ gb,
                      float* __restrict__ gate) {
  int lane = threadIdx.x & 63;
  int n = blockIdx.x * 4 + (threadIdx.x >> 6);
  if (n >= N_FACES) return;
  int e0 = row_ptr[n], e1 = row_ptr[n + 1];
  float4 ern = reinterpret_cast<const float4*>(er)[n];

  float s0 = 0.f, s1 = 0.f, s2 = 0.f, s3 = 0.f;
  float a0 = 0.f, a1 = 0.f, a2 = 0.f, a3 = 0.f;
  if (e0 < e1) {
    int sp = csrc[e0];
    float4 ep = reinterpret_cast<const float4*>(el)[sp];
    const float* fr = f + (size_t)sp * HID;
    float f0 = fr[lane], f1 = fr[lane + 64], f2 = fr[lane + 128], f3 = fr[lane + 192];
    for (int t = e0; t < e1; ++t) {
      int sn = 0; float4 en = ep;
      float g0 = 0.f, g1 = 0.f, g2 = 0.f, g3 = 0.f;
      if (t + 1 < e1) {
        sn = csrc[t + 1];
        en = reinterpret_cast<const float4*>(el)[sn];
        const float* frn = f + (size_t)sn * HID;
        g0 = frn[lane]; g1 = frn[lane + 64]; g2 = frn[lane + 128]; g3 = frn[lane + 192];
      }
      float w, p;
      w = ep.x + ern.x; w = fmaxf(w, 0.2f * w); p = __expf(w); s0 += p; a0 += f0 * p;
      w = ep.y + ern.y; w = fmaxf(w, 0.2f * w); p = __expf(w); s1 += p; a1 += f1 * p;
      w = ep.z + ern.z; w = fmaxf(w, 0.2f * w); p = __expf(w); s2 += p; a2 += f2 * p;
      w = ep.w + ern.w; w = fmaxf(w, 0.2f * w); p = __expf(w); s3 += p; a3 += f3 * p;
      ep = en; f0 = g0; f1 = g1; f2 = g2; f3 = g3;
    }
  }
  a0 *= (s0 > 0.f ? 1.f / s0 : 0.f);
  a1 *= (s1 > 0.f ? 1.f / s1 : 0.f);
  a2 *= (s2 > 0.f ? 1.f / s2 : 0.f);
  a3 *= (s3 > 0.f ? 1.f / s3 : 0.f);

  float y0 = fmaxf(a0 + bias[lane], 0.f);
  float y1 = fmaxf(a1 + bias[lane + 64], 0.f);
  float y2 = fmaxf(a2 + bias[lane + 128], 0.f);
  float y3 = fmaxf(a3 + bias[lane + 192], 0.f);
  float s = y0 + y1 + y2 + y3;
  float q = y0 * y0 + y1 * y1 + y2 * y2 + y3 * y3;
  s = wave_sum(s); q = wave_sum(q);
  float mu = s * (1.f / HID);
  float rs = rsqrtf(fmaxf(q * (1.f / HID) - mu * mu, 0.f) + 1e-5f);
  float h0 = (y0 - mu) * rs * g[lane]       + be[lane];
  float h1 = (y1 - mu) * rs * g[lane + 64]  + be[lane + 64];
  float h2 = (y2 - mu) * rs * g[lane + 128] + be[lane + 128];
  float h3 = (y3 - mu) * rs * g[lane + 192] + be[lane + 192];
  size_t base = (size_t)n * HID;
  h[base + lane]       = h0;
  h[base + lane + 64]  = h1;
  h[base + lane + 128] = h2;
  h[base + lane + 192] = h3;

  if (gw) {  // fused gate score (layer 1 only)
    float p = h0 * gw[lane] + h1 * gw[lane + 64] + h2 * gw[lane + 128] + h3 * gw[lane + 192];
    p = wave_sum(p);
    if (lane == 0) gate[n] = p + gb[0];
  }
}

// ---------- per-graph max of gate: LDS pre-reduction, then global atomics ----------
__global__ void k_gmax(const float* __restrict__ gate, const int* __restrict__ gid,
                       unsigned* __restrict__ gmax_u) {
  __shared__ unsigned sm[NB];
  int t = threadIdx.x;
  if (t < NB) sm[t] = 0u;
  __syncthreads();
  int n = blockIdx.x * blockDim.x + t;
  if (n < N_FACES) atomicMax(&sm[gid[n]], enc_ord(gate[n]));
  __syncthreads();
  if (t < NB && sm[t] != 0u) atomicMax(&gmax_u[t], sm[t]);
}

// ---------- parallel weighted pooling (unnormalized) ----------
#define PCHUNK 125
__global__ void k_psum(const float* __restrict__ h, const float* __restrict__ gate,
                       const int* __restrict__ gid, const unsigned* __restrict__ gmax_u,
                       float* __restrict__ praw, float* __restrict__ gs) {
  int t = threadIdx.x;
  int n0 = blockIdx.x * PCHUNK;
  int n1 = n0 + PCHUNK;
  if (n1 > N_FACES) n1 = N_FACES;
  if (n0 >= N_FACES) return;
  int cur = gid[n0];
  float gm = dec_ord(gmax_u[cur]);
  float acc = 0.f, wsum = 0.f;
  for (int n = n0; n < n1; ++n) {
    int g = gid[n];
    if (g != cur) {
      atomicAdd(&praw[cur * HID + t], acc);
      if (t == 0) atomicAdd(&gs[cur], wsum);
      acc = 0.f; wsum = 0.f; cur = g; gm = dec_ord(gmax_u[cur]);
    }
    float w = __expf(gate[n] - gm);
    acc += w * h[(size_t)n * HID + t];
    wsum += w;
  }
  atomicAdd(&praw[cur * HID + t], acc);
  if (t == 0) atomicAdd(&gs[cur], wsum);
}

__global__ void k_poolnorm(const float* __restrict__ praw, const float* __restrict__ gs,
                           float* __restrict__ pooled) {
  int b = blockIdx.x, c = threadIdx.x;
  pooled[b * HID + c] = praw[b * HID + c] / gs[b];
}

// ---------- output projection + LN ----------
__global__ void k_out(const float* __restrict__ pooled, const float* __restrict__ oW,
                      const float* __restrict__ oB, const float* __restrict__ oG,
                      const float* __restrict__ oBe, float* __restrict__ feat) {
  int b = blockIdx.x;
  int o = threadIdx.x;  // 512 threads
  int lane = o & 63, wid = o >> 6;
  __shared__ float p[HID];
  __shared__ float partS[8], partQ[8];
  __shared__ float shMu, shRs;
  if (o < HID) p[o] = pooled[b * HID + o];
  __syncthreads();
  float a = oB[o];
  for (int k = 0; k < HID; ++k) a += p[k] * oW[k * NOUT + o];
  float y = fmaxf(a, 0.f);
  float s = wave_sum(y), q = wave_sum(y * y);
  if (lane == 0) { partS[wid] = s; partQ[wid] = q; }
  __syncthreads();
  if (o == 0) {
    float S = 0.f, Q = 0.f;
#pragma unroll
    for (int i = 0; i < 8; ++i) { S += partS[i]; Q += partQ[i]; }
    float mu = S * (1.f / NOUT);
    shMu = mu;
    shRs = rsqrtf(fmaxf(Q * (1.f / NOUT) - mu * mu, 0.f) + 1e-5f);
  }
  __syncthreads();
  feat[b * NOUT + o] = (y - shMu) * shRs * oG[o] + oBe[o];
}

extern "C" void kernel_launch(void* const* d_in, const int* in_sizes, int n_in,
                              void* d_out, int out_size, void* d_ws, size_t ws_size,
                              hipStream_t stream) {
  (void)in_sizes; (void)n_in; (void)out_size; (void)ws_size;
  const float* x_face    = (const float*)d_in[0];
  const float* x_edge    = (const float*)d_in[1];
  const float* face_W    = (const float*)d_in[2];
  const float* face_b    = (const float*)d_in[3];
  const float* face_g    = (const float*)d_in[4];
  const float* face_beta = (const float*)d_in[5];
  const float* edge_W    = (const float*)d_in[6];
  const float* edge_b    = (const float*)d_in[7];
  const float* edge_g    = (const float*)d_in[8];
  const float* edge_beta = (const float*)d_in[9];
  const float* g0_W      = (const float*)d_in[10];
  const float* g0_al     = (const float*)d_in[11];
  const float* g0_ar     = (const float*)d_in[12];
  const float* g0_bias   = (const float*)d_in[13];
  const float* g0_g      = (const float*)d_in[14];
  const float* g0_beta   = (const float*)d_in[15];
  const float* g1_W      = (const float*)d_in[16];
  const float* g1_al     = (const float*)d_in[17];
  const float* g1_ar     = (const float*)d_in[18];
  const float* g1_bias   = (const float*)d_in[19];
  const float* g1_g      = (const float*)d_in[20];
  const float* g1_beta   = (const float*)d_in[21];
  const float* gate_W    = (const float*)d_in[22];
  const float* gate_b    = (const float*)d_in[23];
  const float* out_W     = (const float*)d_in[24];
  const float* out_b     = (const float*)d_in[25];
  const float* out_g     = (const float*)d_in[26];
  const float* out_beta  = (const float*)d_in[27];
  const int*   src       = (const int*)d_in[28];
  const int*   dst       = (const int*)d_in[29];
  const int*   gid       = (const int*)d_in[30];

  char* ws = (char*)d_ws;
  size_t off = 0;
  auto take = [&](size_t bytes) -> char* {
    char* pp = ws + off;
    off += (bytes + 255) & ~(size_t)255;
    return pp;
  };
  int*      cnt      = (int*)take((size_t)N_FACES * 4);
  int*      fill     = (int*)take((size_t)N_FACES * 4);
  int*      row_ptr  = (int*)take((size_t)(N_FACES + 1) * 4);
  int*      bsum     = (int*)take((size_t)SCAN_NB * 4);
  int*      csr_src  = (int*)take((size_t)N_EDGES * 4);
  float*    csr_rec  = (float*)take((size_t)N_EDGES * 8 * 4);
  unsigned* gmax_u   = (unsigned*)take(64);
  float*    gs       = (float*)take(64);
  float*    praw     = (float*)take((size_t)NB * HID * 4);
  float*    el       = (float*)take((size_t)N_FACES * 4 * 4);
  float*    er       = (float*)take((size_t)N_FACES * 4 * 4);
  float*    gate     = (float*)take((size_t)N_FACES * 4);
  float*    f        = (float*)take((size_t)N_FACES * HID * 4);

  float* outp   = (float*)d_out;
  float* feat   = outp;
  float* h      = outp + NB * NOUT;
  float* pooled = outp + NB * NOUT + (size_t)N_FACES * HID;

  hipMemsetAsync(cnt, 0, (size_t)N_FACES * 4, stream);
  hipMemsetAsync(fill, 0, (size_t)N_FACES * 4, stream);
  hipMemsetAsync(gmax_u, 0, 64, stream);
  hipMemsetAsync(gs, 0, 64, stream);
  hipMemsetAsync(praw, 0, (size_t)NB * HID * 4, stream);

  k_hist<<<(N_EDGES + 255) / 256, 256, 0, stream>>>(dst, cnt);
  k_scan1<<<SCAN_NB, SCAN_B, 0, stream>>>(cnt, bsum);
  k_scan2<<<1, 64, 0, stream>>>(bsum);
  k_scan3<<<SCAN_NB, SCAN_B, 0, stream>>>(cnt, bsum, row_ptr);
  k_scatter<<<(N_EDGES + 255) / 256, 256, 0, stream>>>(dst, src, x_edge, row_ptr,
                                                       edge_W, edge_b, fill,
                                                       csr_rec, csr_src);

  k_encode<<<N_FACES / 4, 256, 0, stream>>>(x_face, csr_rec, face_W, face_b, face_g, face_beta,
                                            edge_W, edge_b, edge_g, edge_beta,
                                            row_ptr, h);
  // GAT layer 0
  k_gemm_elr<<<(N_FACES + GM - 1) / GM, 256, 0, stream>>>(h, g0_W, g0_al, g0_ar, f, el, er);
  k_gat<<<N_FACES / 4, 256, 0, stream>>>(f, el, er, row_ptr, csr_src,
                                         g0_bias, g0_g, g0_beta, h,
                                         nullptr, nullptr, nullptr);
  // GAT layer 1 (+ fused gate scores)
  k_gemm_elr<<<(N_FACES + GM - 1) / GM, 256, 0, stream>>>(h, g1_W, g1_al, g1_ar, f, el, er);
  k_gat<<<N_FACES / 4, 256, 0, stream>>>(f, el, er, row_ptr, csr_src,
                                         g1_bias, g1_g, g1_beta, h,
                                         gate_W, gate_b, gate);
  // pooling + output head
  k_gmax<<<(N_FACES + 255) / 256, 256, 0, stream>>>(gate, gid, gmax_u);
  k_psum<<<(N_FACES + PCHUNK - 1) / PCHUNK, 256, 0, stream>>>(h, gate, gid, gmax_u, praw, gs);
  k_poolnorm<<<NB, HID, 0, stream>>>(praw, gs, pooled);
  k_out<<<NB, NOUT, 0, stream>>>(pooled, out_W, out_b, out_g, out_beta, feat);
}

// Round 8
// 703.427 us; speedup vs baseline: 1.2862x; 1.0810x over previous
//
#include <hip/hip_runtime.h>

#define N_FACES 50000
#define N_EDGES 800000
#define NB      16
#define HID     256
#define NOUT    512
#define SCAN_B  1024
#define SCAN_NB ((N_FACES + SCAN_B - 1) / SCAN_B)

// ---------- wave helpers ----------
__device__ __forceinline__ float wave_sum(float v) {
#pragma unroll
  for (int o = 32; o; o >>= 1) v += __shfl_xor(v, o, 64);
  return v;
}

// ---------- order-preserving float<->uint encoding (for atomicMax) ----------
__device__ __forceinline__ unsigned enc_ord(float v) {
  unsigned b = __float_as_uint(v);
  return (b & 0x80000000u) ? ~b : (b | 0x80000000u);
}
__device__ __forceinline__ float dec_ord(unsigned e) {
  unsigned b = (e & 0x80000000u) ? (e ^ 0x80000000u) : ~e;
  return __uint_as_float(b);
}

// RNE float->bf16 (finite inputs)
__device__ __forceinline__ unsigned f2bf(float x) {
  unsigned u = __float_as_uint(x);
  return (u + 0x7fffu + ((u >> 16) & 1u)) >> 16;
}

// ---------- CSR build ----------
__global__ void k_hist(const int* __restrict__ dst, int* __restrict__ cnt) {
  int e = blockIdx.x * blockDim.x + threadIdx.x;
  if (e < N_EDGES) atomicAdd(&cnt[dst[e]], 1);
}

// 3-phase parallel exclusive scan of cnt[N_FACES] -> row_ptr[N_FACES+1]
__global__ void k_scan1(const int* __restrict__ cnt, int* __restrict__ bsum) {
  __shared__ int sh[SCAN_B];
  int i = blockIdx.x * SCAN_B + threadIdx.x;
  sh[threadIdx.x] = (i < N_FACES) ? cnt[i] : 0;
  __syncthreads();
  for (int off = SCAN_B / 2; off; off >>= 1) {
    if (threadIdx.x < off) sh[threadIdx.x] += sh[threadIdx.x + off];
    __syncthreads();
  }
  if (threadIdx.x == 0) bsum[blockIdx.x] = sh[0];
}

__global__ void k_scan2(int* __restrict__ bsum) {  // nb <= 64, one wave
  int t = threadIdx.x;
  int v = (t < SCAN_NB) ? bsum[t] : 0;
  int inc = v;
#pragma unroll
  for (int off = 1; off < 64; off <<= 1) {
    int u = __shfl_up(inc, off, 64);
    if (t >= off) inc += u;
  }
  if (t < SCAN_NB) bsum[t] = inc - v;  // exclusive
}

__global__ void k_scan3(const int* __restrict__ cnt, const int* __restrict__ bsum,
                        int* __restrict__ row_ptr) {
  __shared__ int sh[SCAN_B];
  int i = blockIdx.x * SCAN_B + threadIdx.x;
  int v = (i < N_FACES) ? cnt[i] : 0;
  sh[threadIdx.x] = v;
  __syncthreads();
  for (int off = 1; off < SCAN_B; off <<= 1) {
    int x = (threadIdx.x >= off) ? sh[threadIdx.x - off] : 0;
    __syncthreads();
    sh[threadIdx.x] += x;
    __syncthreads();
  }
  if (i < N_FACES) row_ptr[i] = bsum[blockIdx.x] + sh[threadIdx.x] - v;
  if (i == 0) row_ptr[N_FACES] = N_EDGES;
}

// scatter edge {features, LN stats} as one 32B record into CSR order
__global__ void k_scatter(const int* __restrict__ dst, const int* __restrict__ src,
                          const float* __restrict__ xe, const int* __restrict__ row_ptr,
                          const float* __restrict__ eW, const float* __restrict__ eB,
                          int* __restrict__ fill, float* __restrict__ csr_rec,
                          int* __restrict__ csr_src) {
  __shared__ float sw[6][HID];
  __shared__ float sb[HID];
  int t0 = threadIdx.x;
  for (int i = t0; i < 6 * HID; i += 256) sw[i / HID][i % HID] = eW[i];
  for (int i = t0; i < HID; i += 256) sb[i] = eB[i];
  __syncthreads();

  int e = blockIdx.x * blockDim.x + t0;
  if (e >= N_EDGES) return;
  float z[6];
#pragma unroll
  for (int k = 0; k < 6; ++k) z[k] = xe[(size_t)e * 6 + k];
  int d = dst[e];
  int p = atomicAdd(&fill[d], 1);
  int pos = row_ptr[d] + p;
  csr_src[pos] = src[e];

  float s1 = 0.f, s2 = 0.f;
  for (int c = 0; c < HID; c += 4) {
    float4 w4 = *reinterpret_cast<const float4*>(&sb[c]);
#pragma unroll
    for (int k = 0; k < 6; ++k) {
      float4 m4 = *reinterpret_cast<const float4*>(&sw[k][c]);
      w4.x += z[k] * m4.x; w4.y += z[k] * m4.y;
      w4.z += z[k] * m4.z; w4.w += z[k] * m4.w;
    }
    w4.x = fmaxf(w4.x, 0.f); w4.y = fmaxf(w4.y, 0.f);
    w4.z = fmaxf(w4.z, 0.f); w4.w = fmaxf(w4.w, 0.f);
    s1 += (w4.x + w4.y) + (w4.z + w4.w);
    s2 += (w4.x * w4.x + w4.y * w4.y) + (w4.z * w4.z + w4.w * w4.w);
  }
  float mu = s1 * (1.f / HID);
  float rs = rsqrtf(fmaxf(s2 * (1.f / HID) - mu * mu, 0.f) + 1e-5f);
  float4* out = reinterpret_cast<float4*>(csr_rec);
  out[(size_t)pos * 2]     = make_float4(z[0], z[1], z[2], z[3]);
  out[(size_t)pos * 2 + 1] = make_float4(z[4], z[5], mu, rs);
}

// ---------- encoders + mean aggregation (one wave per node; 2 vec loads/edge, prefetched) ----------
__global__ void k_encode(const float* __restrict__ xf, const float* __restrict__ csr_rec,
                         const float* __restrict__ fW, const float* __restrict__ fB,
                         const float* __restrict__ fG, const float* __restrict__ fBe,
                         const float* __restrict__ eW, const float* __restrict__ eB,
                         const float* __restrict__ eG, const float* __restrict__ eBe,
                         const int* __restrict__ row_ptr, float* __restrict__ h) {
  int lane = threadIdx.x & 63;
  int n = blockIdx.x * 4 + (threadIdx.x >> 6);
  if (n >= N_FACES) return;

  // face encoder
  float x[7];
#pragma unroll
  for (int k = 0; k < 7; ++k) x[k] = xf[n * 7 + k];
  float y[4];
#pragma unroll
  for (int j = 0; j < 4; ++j) {
    int c = lane + 64 * j;
    float a = fB[c];
#pragma unroll
    for (int k = 0; k < 7; ++k) a += x[k] * fW[k * HID + c];
    y[j] = fmaxf(a, 0.f);
  }
  float s = y[0] + y[1] + y[2] + y[3];
  float s2 = y[0] * y[0] + y[1] * y[1] + y[2] * y[2] + y[3] * y[3];
  s = wave_sum(s); s2 = wave_sum(s2);
  float mu = s * (1.f / HID);
  float rs = rsqrtf(fmaxf(s2 * (1.f / HID) - mu * mu, 0.f) + 1e-5f);
  float hv[4];
#pragma unroll
  for (int j = 0; j < 4; ++j) {
    int c = lane + 64 * j;
    hv[j] = (y[j] - mu) * rs * fG[c] + fBe[c];
  }

  // hoist edge-encoder params into registers (loop-invariant)
  float ew[6][4], eb[4], eg[4], ebe[4];
#pragma unroll
  for (int j = 0; j < 4; ++j) {
    int c = lane + 64 * j;
    eb[j] = eB[c]; eg[j] = eG[c]; ebe[j] = eBe[c];
#pragma unroll
    for (int k = 0; k < 6; ++k) ew[k][j] = eW[k * HID + c];
  }

  int e0 = row_ptr[n], e1 = row_ptr[n + 1];
  float acc[4] = {0.f, 0.f, 0.f, 0.f};
  const float4* rec = reinterpret_cast<const float4*>(csr_rec);
  float4 pa, pb;
  if (e0 < e1) {
    pa = rec[(size_t)e0 * 2];
    pb = rec[(size_t)e0 * 2 + 1];
  }
  for (int t = e0; t < e1; ++t) {
    float4 ca = pa, cb = pb;
    if (t + 1 < e1) {
      pa = rec[(size_t)(t + 1) * 2];
      pb = rec[(size_t)(t + 1) * 2 + 1];
    }
    float z0 = ca.x, z1 = ca.y, z2 = ca.z, z3 = ca.w, z4 = cb.x, z5 = cb.y;
    float emu = cb.z, ers = cb.w;
#pragma unroll
    for (int j = 0; j < 4; ++j) {
      float a = eb[j];
      a = fmaf(z0, ew[0][j], a); a = fmaf(z1, ew[1][j], a);
      a = fmaf(z2, ew[2][j], a); a = fmaf(z3, ew[3][j], a);
      a = fmaf(z4, ew[4][j], a); a = fmaf(z5, ew[5][j], a);
      a = fmaxf(a, 0.f);
      acc[j] += (a - emu) * (ers * eg[j]) + ebe[j];
    }
  }
  float inv = (e1 > e0) ? 1.f / (float)(e1 - e0) : 0.f;
#pragma unroll
  for (int j = 0; j < 4; ++j) h[(size_t)n * HID + lane + 64 * j] = hv[j] + acc[j] * inv;
}

// ---------- f = h @ W with fused el/er; f stored as packed bf16 pairs ----------
#define GM 32
__global__ void k_gemm_elr(const float* __restrict__ h, const float* __restrict__ W,
                           const float* __restrict__ al, const float* __restrict__ ar,
                           unsigned* __restrict__ fb, float* __restrict__ el,
                           float* __restrict__ er) {
  __shared__ float hs[GM][HID];
  int n0 = blockIdx.x * GM;
  int tid = threadIdx.x;
  int q = tid & 63;
  int wv = tid >> 6;

  {
    const float4* hsrc = reinterpret_cast<const float4*>(h);
    float4* hdst = reinterpret_cast<float4*>(&hs[0][0]);
    for (int i = tid; i < GM * HID / 4; i += 256) {
      int n = n0 + (i >> 6);
      hdst[i] = (n < N_FACES) ? hsrc[(size_t)n0 * 64 + i] : make_float4(0.f, 0.f, 0.f, 0.f);
    }
  }
  __syncthreads();

  float4 acc[8];
#pragma unroll
  for (int m = 0; m < 8; ++m) acc[m] = make_float4(0.f, 0.f, 0.f, 0.f);

  const float* Wq = W + 4 * q;
  for (int k = 0; k < HID; k += 4) {
    float4 w0 = *reinterpret_cast<const float4*>(Wq + (size_t)(k + 0) * HID);
    float4 w1 = *reinterpret_cast<const float4*>(Wq + (size_t)(k + 1) * HID);
    float4 w2 = *reinterpret_cast<const float4*>(Wq + (size_t)(k + 2) * HID);
    float4 w3 = *reinterpret_cast<const float4*>(Wq + (size_t)(k + 3) * HID);
#pragma unroll
    for (int m = 0; m < 8; ++m) {
      float4 h4 = *reinterpret_cast<const float4*>(&hs[wv * 8 + m][k]);
      acc[m].x = fmaf(h4.x, w0.x, acc[m].x); acc[m].y = fmaf(h4.x, w0.y, acc[m].y);
      acc[m].z = fmaf(h4.x, w0.z, acc[m].z); acc[m].w = fmaf(h4.x, w0.w, acc[m].w);
      acc[m].x = fmaf(h4.y, w1.x, acc[m].x); acc[m].y = fmaf(h4.y, w1.y, acc[m].y);
      acc[m].z = fmaf(h4.y, w1.z, acc[m].z); acc[m].w = fmaf(h4.y, w1.w, acc[m].w);
      acc[m].x = fmaf(h4.z, w2.x, acc[m].x); acc[m].y = fmaf(h4.z, w2.y, acc[m].y);
      acc[m].z = fmaf(h4.z, w2.z, acc[m].z); acc[m].w = fmaf(h4.z, w2.w, acc[m].w);
      acc[m].x = fmaf(h4.w, w3.x, acc[m].x); acc[m].y = fmaf(h4.w, w3.y, acc[m].y);
      acc[m].z = fmaf(h4.w, w3.z, acc[m].z); acc[m].w = fmaf(h4.w, w3.w, acc[m].w);
    }
  }

  int hd = q >> 4;
  float4 alv = *reinterpret_cast<const float4*>(al + 4 * q);
  float4 arv = *reinterpret_cast<const float4*>(ar + 4 * q);
#pragma unroll
  for (int m = 0; m < 8; ++m) {
    int n = n0 + wv * 8 + m;
    if (n >= N_FACES) break;
    unsigned p0 = f2bf(acc[m].x) | (f2bf(acc[m].y) << 16);
    unsigned p1 = f2bf(acc[m].z) | (f2bf(acc[m].w) << 16);
    *reinterpret_cast<uint2*>(fb + (size_t)n * 128 + 2 * q) = make_uint2(p0, p1);
    float pl = acc[m].x * alv.x + acc[m].y * alv.y + acc[m].z * alv.z + acc[m].w * alv.w;
    float pr = acc[m].x * arv.x + acc[m].y * arv.y + acc[m].z * arv.z + acc[m].w * arv.w;
#pragma unroll
    for (int o = 1; o < 16; o <<= 1) {
      pl += __shfl_xor(pl, o, 64);
      pr += __shfl_xor(pr, o, 64);
    }
    if ((q & 15) == 0) {
      el[n * 4 + hd] = pl;
      er[n * 4 + hd] = pr;
    }
  }
}

// ---------- GAT: bf16 f gather (2 dwords/lane/edge), lane owns cols {2l,2l+1,128+2l,128+2l+1} ----------
__global__ void k_gat(const unsigned* __restrict__ fb, const float* __restrict__ el,
                      const float* __restrict__ er, const int* __restrict__ row_ptr,
                      const int* __restrict__ csrc,
                      const float* __restrict__ bias, const float* __restrict__ g,
                      const float* __restrict__ be, float* __restrict__ h,
                      const float* __restrict__ gw, const float* __restrict__ gb,
                      float* __restrict__ gate) {
  int lane = threadIdx.x & 63;
  int n = blockIdx.x * 4 + (threadIdx.x >> 6);
  if (n >= N_FACES) return;
  int e0 = row_ptr[n], e1 = row_ptr[n + 1];
  float4 ern = reinterpret_cast<const float4*>(er)[n];
  int hh = lane >> 5;  // this lane's heads: hh and hh+2
  float ernA = hh ? ern.y : ern.x;
  float ernB = hh ? ern.w : ern.z;

  float sA = 0.f, sB = 0.f;
  float aA0 = 0.f, aA1 = 0.f, aB0 = 0.f, aB1 = 0.f;
  if (e0 < e1) {
    int sp = csrc[e0];
    float4 ep = reinterpret_cast<const float4*>(el)[sp];
    unsigned u0 = fb[(size_t)sp * 128 + lane];
    unsigned u1 = fb[(size_t)sp * 128 + 64 + lane];
    for (int t = e0; t < e1; ++t) {
      float4 ec = ep; unsigned v0 = u0, v1 = u1;
      if (t + 1 < e1) {
        int sn = csrc[t + 1];
        ep = reinterpret_cast<const float4*>(el)[sn];
        u0 = fb[(size_t)sn * 128 + lane];
        u1 = fb[(size_t)sn * 128 + 64 + lane];
      }
      float elA = hh ? ec.y : ec.x;
      float elB = hh ? ec.w : ec.z;
      float w, pA, pB;
      w = elA + ernA; w = fmaxf(w, 0.2f * w); pA = __expf(w); sA += pA;
      w = elB + ernB; w = fmaxf(w, 0.2f * w); pB = __expf(w); sB += pB;
      aA0 = fmaf(__uint_as_float(v0 << 16), pA, aA0);
      aA1 = fmaf(__uint_as_float(v0 & 0xffff0000u), pA, aA1);
      aB0 = fmaf(__uint_as_float(v1 << 16), pB, aB0);
      aB1 = fmaf(__uint_as_float(v1 & 0xffff0000u), pB, aB1);
    }
  }
  float iA = sA > 0.f ? 1.f / sA : 0.f;
  float iB = sB > 0.f ? 1.f / sB : 0.f;
  int c0 = 2 * lane, c2 = 128 + 2 * lane;
  float2 bb0 = *reinterpret_cast<const float2*>(bias + c0);
  float2 bb2 = *reinterpret_cast<const float2*>(bias + c2);
  float y0 = fmaxf(aA0 * iA + bb0.x, 0.f);
  float y1 = fmaxf(aA1 * iA + bb0.y, 0.f);
  float y2 = fmaxf(aB0 * iB + bb2.x, 0.f);
  float y3 = fmaxf(aB1 * iB + bb2.y, 0.f);
  float s = y0 + y1 + y2 + y3;
  float q = y0 * y0 + y1 * y1 + y2 * y2 + y3 * y3;
  s = wave_sum(s); q = wave_sum(q);
  float mu = s * (1.f / HID);
  float rs = rsqrtf(fmaxf(q * (1.f / HID) - mu * mu, 0.f) + 1e-5f);
  float2 gg0 = *reinterpret_cast<const float2*>(g + c0);
  float2 gg2 = *reinterpret_cast<const float2*>(g + c2);
  float2 ee0 = *reinterpret_cast<const float2*>(be + c0);
  float2 ee2 = *reinterpret_cast<const float2*>(be + c2);
  float h0 = (y0 - mu) * rs * gg0.x + ee0.x;
  float h1 = (y1 - mu) * rs * gg0.y + ee0.y;
  float h2 = (y2 - mu) * rs * gg2.x + ee2.x;
  float h3 = (y3 - mu) * rs * gg2.y + ee2.y;
  size_t base = (size_t)n * HID;
  *reinterpret_cast<float2*>(h + base + c0) = make_float2(h0, h1);
  *reinterpret_cast<float2*>(h + base + c2) = make_float2(h2, h3);

  if (gw) {  // fused gate score (layer 1 only)
    float2 w0 = *reinterpret_cast<const float2*>(gw + c0);
    float2 w2 = *reinterpret_cast<const float2*>(gw + c2);
    float p = h0 * w0.x + h1 * w0.y + h2 * w2.x + h3 * w2.y;
    p = wave_sum(p);
    if (lane == 0) gate[n] = p + gb[0];
  }
}

// ---------- per-graph max of gate: LDS pre-reduction, then global atomics ----------
__global__ void k_gmax(const float* __restrict__ gate, const int* __restrict__ gid,
                       unsigned* __restrict__ gmax_u) {
  __shared__ unsigned sm[NB];
  int t = threadIdx.x;
  if (t < NB) sm[t] = 0u;
  __syncthreads();
  int n = blockIdx.x * blockDim.x + t;
  if (n < N_FACES) atomicMax(&sm[gid[n]], enc_ord(gate[n]));
  __syncthreads();
  if (t < NB && sm[t] != 0u) atomicMax(&gmax_u[t], sm[t]);
}

// ---------- parallel weighted pooling (unnormalized) ----------
#define PCHUNK 125
__global__ void k_psum(const float* __restrict__ h, const float* __restrict__ gate,
                       const int* __restrict__ gid, const unsigned* __restrict__ gmax_u,
                       float* __restrict__ praw, float* __restrict__ gs) {
  int t = threadIdx.x;
  int n0 = blockIdx.x * PCHUNK;
  int n1 = n0 + PCHUNK;
  if (n1 > N_FACES) n1 = N_FACES;
  if (n0 >= N_FACES) return;
  int cur = gid[n0];
  float gm = dec_ord(gmax_u[cur]);
  float acc = 0.f, wsum = 0.f;
  for (int n = n0; n < n1; ++n) {
    int g = gid[n];
    if (g != cur) {
      atomicAdd(&praw[cur * HID + t], acc);
      if (t == 0) atomicAdd(&gs[cur], wsum);
      acc = 0.f; wsum = 0.f; cur = g; gm = dec_ord(gmax_u[cur]);
    }
    float w = __expf(gate[n] - gm);
    acc += w * h[(size_t)n * HID + t];
    wsum += w;
  }
  atomicAdd(&praw[cur * HID + t], acc);
  if (t == 0) atomicAdd(&gs[cur], wsum);
}

__global__ void k_poolnorm(const float* __restrict__ praw, const float* __restrict__ gs,
                           float* __restrict__ pooled) {
  int b = blockIdx.x, c = threadIdx.x;
  pooled[b * HID + c] = praw[b * HID + c] / gs[b];
}

// ---------- output projection + LN ----------
__global__ void k_out(const float* __restrict__ pooled, const float* __restrict__ oW,
                      const float* __restrict__ oB, const float* __restrict__ oG,
                      const float* __restrict__ oBe, float* __restrict__ feat) {
  int b = blockIdx.x;
  int o = threadIdx.x;  // 512 threads
  int lane = o & 63, wid = o >> 6;
  __shared__ float p[HID];
  __shared__ float partS[8], partQ[8];
  __shared__ float shMu, shRs;
  if (o < HID) p[o] = pooled[b * HID + o];
  __syncthreads();
  float a = oB[o];
  for (int k = 0; k < HID; ++k) a += p[k] * oW[k * NOUT + o];
  float y = fmaxf(a, 0.f);
  float s = wave_sum(y), q = wave_sum(y * y);
  if (lane == 0) { partS[wid] = s; partQ[wid] = q; }
  __syncthreads();
  if (o == 0) {
    float S = 0.f, Q = 0.f;
#pragma unroll
    for (int i = 0; i < 8; ++i) { S += partS[i]; Q += partQ[i]; }
    float mu = S * (1.f / NOUT);
    shMu = mu;
    shRs = rsqrtf(fmaxf(Q * (1.f / NOUT) - mu * mu, 0.f) + 1e-5f);
  }
  __syncthreads();
  feat[b * NOUT + o] = (y - shMu) * shRs * oG[o] + oBe[o];
}

extern "C" void kernel_launch(void* const* d_in, const int* in_sizes, int n_in,
                              void* d_out, int out_size, void* d_ws, size_t ws_size,
                              hipStream_t stream) {
  (void)in_sizes; (void)n_in; (void)out_size; (void)ws_size;
  const float* x_face    = (const float*)d_in[0];
  const float* x_edge    = (const float*)d_in[1];
  const float* face_W    = (const float*)d_in[2];
  const float* face_b    = (const float*)d_in[3];
  const float* face_g    = (const float*)d_in[4];
  const float* face_beta = (const float*)d_in[5];
  const float* edge_W    = (const float*)d_in[6];
  const float* edge_b    = (const float*)d_in[7];
  const float* edge_g    = (const float*)d_in[8];
  const float* edge_beta = (const float*)d_in[9];
  const float* g0_W      = (const float*)d_in[10];
  const float* g0_al     = (const float*)d_in[11];
  const float* g0_ar     = (const float*)d_in[12];
  const float* g0_bias   = (const float*)d_in[13];
  const float* g0_g      = (const float*)d_in[14];
  const float* g0_beta   = (const float*)d_in[15];
  const float* g1_W      = (const float*)d_in[16];
  const float* g1_al     = (const float*)d_in[17];
  const float* g1_ar     = (const float*)d_in[18];
  const float* g1_bias   = (const float*)d_in[19];
  const float* g1_g      = (const float*)d_in[20];
  const float* g1_beta   = (const float*)d_in[21];
  const float* gate_W    = (const float*)d_in[22];
  const float* gate_b    = (const float*)d_in[23];
  const float* out_W     = (const float*)d_in[24];
  const float* out_b     = (const float*)d_in[25];
  const float* out_g     = (const float*)d_in[26];
  const float* out_beta  = (const float*)d_in[27];
  const int*   src       = (const int*)d_in[28];
  const int*   dst       = (const int*)d_in[29];
  const int*   gid       = (const int*)d_in[30];

  char* ws = (char*)d_ws;
  size_t off = 0;
  auto take = [&](size_t bytes) -> char* {
    char* pp = ws + off;
    off += (bytes + 255) & ~(size_t)255;
    return pp;
  };
  int*      cnt      = (int*)take((size_t)N_FACES * 4);
  int*      fill     = (int*)take((size_t)N_FACES * 4);
  int*      row_ptr  = (int*)take((size_t)(N_FACES + 1) * 4);
  int*      bsum     = (int*)take((size_t)SCAN_NB * 4);
  int*      csr_src  = (int*)take((size_t)N_EDGES * 4);
  float*    csr_rec  = (float*)take((size_t)N_EDGES * 8 * 4);
  unsigned* gmax_u   = (unsigned*)take(64);
  float*    gs       = (float*)take(64);
  float*    praw     = (float*)take((size_t)NB * HID * 4);
  float*    el       = (float*)take((size_t)N_FACES * 4 * 4);
  float*    er       = (float*)take((size_t)N_FACES * 4 * 4);
  float*    gate     = (float*)take((size_t)N_FACES * 4);
  unsigned* fbuf     = (unsigned*)take((size_t)N_FACES * 128 * 4);

  float* outp   = (float*)d_out;
  float* feat   = outp;
  float* h      = outp + NB * NOUT;
  float* pooled = outp + NB * NOUT + (size_t)N_FACES * HID;

  hipMemsetAsync(cnt, 0, (size_t)N_FACES * 4, stream);
  hipMemsetAsync(fill, 0, (size_t)N_FACES * 4, stream);
  hipMemsetAsync(gmax_u, 0, 64, stream);
  hipMemsetAsync(gs, 0, 64, stream);
  hipMemsetAsync(praw, 0, (size_t)NB * HID * 4, stream);

  k_hist<<<(N_EDGES + 255) / 256, 256, 0, stream>>>(dst, cnt);
  k_scan1<<<SCAN_NB, SCAN_B, 0, stream>>>(cnt, bsum);
  k_scan2<<<1, 64, 0, stream>>>(bsum);
  k_scan3<<<SCAN_NB, SCAN_B, 0, stream>>>(cnt, bsum, row_ptr);
  k_scatter<<<(N_EDGES + 255) / 256, 256, 0, stream>>>(dst, src, x_edge, row_ptr,
                                                       edge_W, edge_b, fill,
                                                       csr_rec, csr_src);

  k_encode<<<N_FACES / 4, 256, 0, stream>>>(x_face, csr_rec, face_W, face_b, face_g, face_beta,
                                            edge_W, edge_b, edge_g, edge_beta,
                                            row_ptr, h);
  // GAT layer 0
  k_gemm_elr<<<(N_FACES + GM - 1) / GM, 256, 0, stream>>>(h, g0_W, g0_al, g0_ar, fbuf, el, er);
  k_gat<<<N_FACES / 4, 256, 0, stream>>>(fbuf, el, er, row_ptr, csr_src,
                                         g0_bias, g0_g, g0_beta, h,
                                         nullptr, nullptr, nullptr);
  // GAT layer 1 (+ fused gate scores)
  k_gemm_elr<<<(N_FACES + GM - 1) / GM, 256, 0, stream>>>(h, g1_W, g1_al, g1_ar, fbuf, el, er);
  k_gat<<<N_FACES / 4, 256, 0, stream>>>(fbuf, el, er, row_ptr, csr_src,
                                         g1_bias, g1_g, g1_beta, h,
                                         gate_W, gate_b, gate);
  // pooling + output head
  k_gmax<<<(N_FACES + 255) / 256, 256, 0, stream>>>(gate, gid, gmax_u);
  k_psum<<<(N_FACES + PCHUNK - 1) / PCHUNK, 256, 0, stream>>>(h, gate, gid, gmax_u, praw, gs);
  k_poolnorm<<<NB, HID, 0, stream>>>(praw, gs, pooled);
  k_out<<<NB, NOUT, 0, stream>>>(pooled, out_W, out_b, out_g, out_beta, feat);
}

// Round 9
// 639.931 us; speedup vs baseline: 1.4138x; 1.0992x over previous
//
#include <hip/hip_runtime.h>

#define N_FACES 50000
#define N_EDGES 800000
#define NB      16
#define HID     256
#define NOUT    512
#define SCAN_B  1024
#define SCAN_NB ((N_FACES + SCAN_B - 1) / SCAN_B)
#define NT      (N_FACES / 16)   // 3125 MFMA node-tiles (exact)

typedef __attribute__((ext_vector_type(8))) short short8v;
typedef __attribute__((ext_vector_type(4))) float float4v;
union U8 { uint4 u; short8v s; };

// ---------- wave helpers ----------
__device__ __forceinline__ float wave_sum(float v) {
#pragma unroll
  for (int o = 32; o; o >>= 1) v += __shfl_xor(v, o, 64);
  return v;
}

// ---------- order-preserving float<->uint encoding (for atomicMax) ----------
__device__ __forceinline__ unsigned enc_ord(float v) {
  unsigned b = __float_as_uint(v);
  return (b & 0x80000000u) ? ~b : (b | 0x80000000u);
}
__device__ __forceinline__ float dec_ord(unsigned e) {
  unsigned b = (e & 0x80000000u) ? (e ^ 0x80000000u) : ~e;
  return __uint_as_float(b);
}

// RNE float->bf16 (finite inputs)
__device__ __forceinline__ unsigned f2bf(float x) {
  unsigned u = __float_as_uint(x);
  return (u + 0x7fffu + ((u >> 16) & 1u)) >> 16;
}
__device__ __forceinline__ float bf_lo(unsigned u) { return __uint_as_float(u << 16); }
__device__ __forceinline__ float bf_hi(unsigned u) { return __uint_as_float(u & 0xffff0000u); }

// ---------- CSR build ----------
__global__ void k_hist(const int* __restrict__ dst, int* __restrict__ cnt) {
  int e = blockIdx.x * blockDim.x + threadIdx.x;
  if (e < N_EDGES) atomicAdd(&cnt[dst[e]], 1);
}

__global__ void k_scan1(const int* __restrict__ cnt, int* __restrict__ bsum) {
  __shared__ int sh[SCAN_B];
  int i = blockIdx.x * SCAN_B + threadIdx.x;
  sh[threadIdx.x] = (i < N_FACES) ? cnt[i] : 0;
  __syncthreads();
  for (int off = SCAN_B / 2; off; off >>= 1) {
    if (threadIdx.x < off) sh[threadIdx.x] += sh[threadIdx.x + off];
    __syncthreads();
  }
  if (threadIdx.x == 0) bsum[blockIdx.x] = sh[0];
}

__global__ void k_scan2(int* __restrict__ bsum) {  // nb <= 64, one wave
  int t = threadIdx.x;
  int v = (t < SCAN_NB) ? bsum[t] : 0;
  int inc = v;
#pragma unroll
  for (int off = 1; off < 64; off <<= 1) {
    int u = __shfl_up(inc, off, 64);
    if (t >= off) inc += u;
  }
  if (t < SCAN_NB) bsum[t] = inc - v;  // exclusive
}

__global__ void k_scan3(const int* __restrict__ cnt, const int* __restrict__ bsum,
                        int* __restrict__ row_ptr) {
  __shared__ int sh[SCAN_B];
  int i = blockIdx.x * SCAN_B + threadIdx.x;
  int v = (i < N_FACES) ? cnt[i] : 0;
  sh[threadIdx.x] = v;
  __syncthreads();
  for (int off = 1; off < SCAN_B; off <<= 1) {
    int x = (threadIdx.x >= off) ? sh[threadIdx.x - off] : 0;
    __syncthreads();
    sh[threadIdx.x] += x;
    __syncthreads();
  }
  if (i < N_FACES) row_ptr[i] = bsum[blockIdx.x] + sh[threadIdx.x] - v;
  if (i == 0) row_ptr[N_FACES] = N_EDGES;
}

// ---------- scatter: 4 lanes per edge; 16B record {z bf16 x6, mu bf16, rs bf16} ----------
__global__ void k_scatter(const int* __restrict__ dst, const int* __restrict__ src,
                          const float* __restrict__ xe, const int* __restrict__ row_ptr,
                          const float* __restrict__ eW, const float* __restrict__ eB,
                          int* __restrict__ fill, uint4* __restrict__ rec16,
                          int* __restrict__ csr_src) {
  __shared__ float sw[6][HID];
  __shared__ float sb[HID];
  int t = threadIdx.x;
  for (int i = t; i < 6 * HID; i += 256) sw[i / HID][i % HID] = eW[i];
  for (int i = t; i < HID; i += 256) sb[i] = eB[i];
  __syncthreads();

  int e = blockIdx.x * 64 + (t >> 2);   // grid sized exactly: 12500 blocks
  int seg = t & 3;
  unsigned zb[6];
  float z[6];
#pragma unroll
  for (int k = 0; k < 6; ++k) {
    zb[k] = f2bf(xe[(size_t)e * 6 + k]);
    z[k] = __uint_as_float(zb[k] << 16);   // stats from bf16-rounded z (consistent)
  }
  int pos = 0;
  if (seg == 0) {
    int d = dst[e];
    int p = atomicAdd(&fill[d], 1);
    pos = row_ptr[d] + p;
  }
  pos = __shfl(pos, (t & 63) & ~3, 64);

  float s1 = 0.f, s2 = 0.f;
  int cbase = seg * 64;
  for (int c = cbase; c < cbase + 64; c += 4) {
    float4 w4 = *reinterpret_cast<const float4*>(&sb[c]);
#pragma unroll
    for (int k = 0; k < 6; ++k) {
      float4 m4 = *reinterpret_cast<const float4*>(&sw[k][c]);
      w4.x = fmaf(z[k], m4.x, w4.x); w4.y = fmaf(z[k], m4.y, w4.y);
      w4.z = fmaf(z[k], m4.z, w4.z); w4.w = fmaf(z[k], m4.w, w4.w);
    }
    w4.x = fmaxf(w4.x, 0.f); w4.y = fmaxf(w4.y, 0.f);
    w4.z = fmaxf(w4.z, 0.f); w4.w = fmaxf(w4.w, 0.f);
    s1 += (w4.x + w4.y) + (w4.z + w4.w);
    s2 += (w4.x * w4.x + w4.y * w4.y) + (w4.z * w4.z + w4.w * w4.w);
  }
  s1 += __shfl_xor(s1, 1, 64); s1 += __shfl_xor(s1, 2, 64);
  s2 += __shfl_xor(s2, 1, 64); s2 += __shfl_xor(s2, 2, 64);
  if (seg == 0) {
    float mu = s1 * (1.f / HID);
    float rs = rsqrtf(fmaxf(s2 * (1.f / HID) - mu * mu, 0.f) + 1e-5f);
    csr_src[pos] = src[e];
    rec16[pos] = make_uint4(zb[0] | (zb[1] << 16), zb[2] | (zb[3] << 16),
                            zb[4] | (zb[5] << 16), f2bf(mu) | (f2bf(rs) << 16));
  }
}

// ---------- encoders + mean aggregation; writes h fp32 + packed bf16 hbd ----------
__global__ void k_encode(const float* __restrict__ xf, const uint4* __restrict__ rec16,
                         const float* __restrict__ fW, const float* __restrict__ fB,
                         const float* __restrict__ fG, const float* __restrict__ fBe,
                         const float* __restrict__ eW, const float* __restrict__ eB,
                         const float* __restrict__ eG, const float* __restrict__ eBe,
                         const int* __restrict__ row_ptr, float* __restrict__ h,
                         unsigned* __restrict__ hbd) {
  int lane = threadIdx.x & 63;
  int n = blockIdx.x * 4 + (threadIdx.x >> 6);
  if (n >= N_FACES) return;

  // face encoder
  float x[7];
#pragma unroll
  for (int k = 0; k < 7; ++k) x[k] = xf[n * 7 + k];
  float y[4];
#pragma unroll
  for (int j = 0; j < 4; ++j) {
    int c = lane + 64 * j;
    float a = fB[c];
#pragma unroll
    for (int k = 0; k < 7; ++k) a += x[k] * fW[k * HID + c];
    y[j] = fmaxf(a, 0.f);
  }
  float s = y[0] + y[1] + y[2] + y[3];
  float s2 = y[0] * y[0] + y[1] * y[1] + y[2] * y[2] + y[3] * y[3];
  s = wave_sum(s); s2 = wave_sum(s2);
  float mu = s * (1.f / HID);
  float rs = rsqrtf(fmaxf(s2 * (1.f / HID) - mu * mu, 0.f) + 1e-5f);
  float hv[4];
#pragma unroll
  for (int j = 0; j < 4; ++j) {
    int c = lane + 64 * j;
    hv[j] = (y[j] - mu) * rs * fG[c] + fBe[c];
  }

  // hoist edge-encoder params (loop-invariant)
  float ew[6][4], eb[4], eg[4], ebe[4];
#pragma unroll
  for (int j = 0; j < 4; ++j) {
    int c = lane + 64 * j;
    eb[j] = eB[c]; eg[j] = eG[c]; ebe[j] = eBe[c];
#pragma unroll
    for (int k = 0; k < 6; ++k) ew[k][j] = eW[k * HID + c];
  }

  int e0 = row_ptr[n], e1 = row_ptr[n + 1];
  float acc[4] = {0.f, 0.f, 0.f, 0.f};
  uint4 pf;
  if (e0 < e1) pf = rec16[e0];
  for (int t = e0; t < e1; ++t) {
    uint4 cu = pf;
    if (t + 1 < e1) pf = rec16[t + 1];
    float z0 = bf_lo(cu.x), z1 = bf_hi(cu.x), z2 = bf_lo(cu.y), z3 = bf_hi(cu.y);
    float z4 = bf_lo(cu.z), z5 = bf_hi(cu.z);
    float emu = bf_lo(cu.w), ers = bf_hi(cu.w);
#pragma unroll
    for (int j = 0; j < 4; ++j) {
      float a = eb[j];
      a = fmaf(z0, ew[0][j], a); a = fmaf(z1, ew[1][j], a);
      a = fmaf(z2, ew[2][j], a); a = fmaf(z3, ew[3][j], a);
      a = fmaf(z4, ew[4][j], a); a = fmaf(z5, ew[5][j], a);
      a = fmaxf(a, 0.f);
      acc[j] += (a - emu) * (ers * eg[j]) + ebe[j];
    }
  }
  float inv = (e1 > e0) ? 1.f / (float)(e1 - e0) : 0.f;
  float hval[4];
#pragma unroll
  for (int j = 0; j < 4; ++j) {
    hval[j] = hv[j] + acc[j] * inv;
    h[(size_t)n * HID + lane + 64 * j] = hval[j];
  }
  // packed bf16 h: dword idx = global_col/2; lane l owns cols l+64j, partner l^1
#pragma unroll
  for (int j = 0; j < 4; ++j) {
    float other = __shfl_xor(hval[j], 1, 64);
    if (!(lane & 1))
      hbd[(size_t)n * 128 + 32 * j + (lane >> 1)] = f2bf(hval[j]) | (f2bf(other) << 16);
  }
}

// ---------- pack W (fp32 [K][256]) into MFMA B-fragment layout (bf16) ----------
__global__ void k_packW(const float* __restrict__ W, uint4* __restrict__ Wp) {
  int i = blockIdx.x * 256 + threadIdx.x;  // 16ct * 8ks * 64lane = 8192
  int lane = i & 63, ks = (i >> 6) & 7, ct = i >> 9;
  int kbase = ks * 32 + (lane >> 4) * 8;
  int col = ct * 16 + (lane & 15);
  unsigned d[4];
#pragma unroll
  for (int r = 0; r < 4; ++r) {
    unsigned lo = f2bf(W[(size_t)(kbase + 2 * r) * HID + col]);
    unsigned hi = f2bf(W[(size_t)(kbase + 2 * r + 1) * HID + col]);
    d[r] = lo | (hi << 16);
  }
  Wp[i] = make_uint4(d[0], d[1], d[2], d[3]);
}

// ---------- MFMA GEMM: f=h@W (bf16), fused el/er + fb-layout write ----------
__global__ void k_gemm_mfma(const unsigned* __restrict__ hbd, const uint4* __restrict__ Wp,
                            const float* __restrict__ al, const float* __restrict__ ar,
                            unsigned* __restrict__ fb, float* __restrict__ el,
                            float* __restrict__ er) {
  int tile = blockIdx.x * 4 + (threadIdx.x >> 6);
  if (tile >= NT) return;
  int lane = threadIdx.x & 63;
  int c = lane & 15;   // A-row / B,D-col within tile
  int kg = lane >> 4;  // k-group
  int n0 = tile * 16;

  uint4 afrag[8];
#pragma unroll
  for (int ks = 0; ks < 8; ++ks)
    afrag[ks] = *reinterpret_cast<const uint4*>(hbd + (size_t)(n0 + c) * 128 + ks * 16 + kg * 4);

  float4v acc[16];
#pragma unroll
  for (int ct = 0; ct < 16; ++ct) acc[ct] = (float4v){0.f, 0.f, 0.f, 0.f};
#pragma unroll
  for (int ct = 0; ct < 16; ++ct) {
#pragma unroll
    for (int ks = 0; ks < 8; ++ks) {
      U8 a, b;
      a.u = afrag[ks];
      b.u = Wp[(ct * 8 + ks) * 64 + lane];
      acc[ct] = __builtin_amdgcn_mfma_f32_16x16x32_bf16(a.s, b.s, acc[ct], 0, 0, 0);
    }
  }

  // fb write (k_gat layout: dword = global_col/2): pack pair via shfl_xor(1)
#pragma unroll
  for (int ct = 0; ct < 16; ++ct) {
#pragma unroll
    for (int reg = 0; reg < 4; ++reg) {
      float v = acc[ct][reg];
      float vo = __shfl_xor(v, 1, 64);
      if (!(lane & 1)) {
        int nd = n0 + kg * 4 + reg;
        fb[(size_t)nd * 128 + ct * 8 + (c >> 1)] = f2bf(v) | (f2bf(vo) << 16);
      }
    }
  }

  // el/er: reduce over 16 cols per tile-col-group; head = ct>>2
  float alr[16], arr[16];
#pragma unroll
  for (int ct = 0; ct < 16; ++ct) {
    alr[ct] = al[ct * 16 + c];
    arr[ct] = ar[ct * 16 + c];
  }
#pragma unroll
  for (int hd = 0; hd < 4; ++hd) {
#pragma unroll
    for (int reg = 0; reg < 4; ++reg) {
      float pl = 0.f, pr = 0.f;
#pragma unroll
      for (int q = 0; q < 4; ++q) {
        int ct = hd * 4 + q;
        pl = fmaf(acc[ct][reg], alr[ct], pl);
        pr = fmaf(acc[ct][reg], arr[ct], pr);
      }
#pragma unroll
      for (int o = 1; o < 16; o <<= 1) {
        pl += __shfl_xor(pl, o, 64);
        pr += __shfl_xor(pr, o, 64);
      }
      if (c == 0) {
        int nd = n0 + kg * 4 + reg;
        el[nd * 4 + hd] = pl;
        er[nd * 4 + hd] = pr;
      }
    }
  }
}

// ---------- GAT: bf16 f gather; optional hbd pack-out (layer0) and fused gate (layer1) ----------
__global__ void k_gat(const unsigned* __restrict__ fb, const float* __restrict__ el,
                      const float* __restrict__ er, const int* __restrict__ row_ptr,
                      const int* __restrict__ csrc,
                      const float* __restrict__ bias, const float* __restrict__ g,
                      const float* __restrict__ be, float* __restrict__ h,
                      unsigned* __restrict__ hbd,
                      const float* __restrict__ gw, const float* __restrict__ gb,
                      float* __restrict__ gate) {
  int lane = threadIdx.x & 63;
  int n = blockIdx.x * 4 + (threadIdx.x >> 6);
  if (n >= N_FACES) return;
  int e0 = row_ptr[n], e1 = row_ptr[n + 1];
  float4 ern = reinterpret_cast<const float4*>(er)[n];
  int hh = lane >> 5;  // this lane's heads: hh and hh+2
  float ernA = hh ? ern.y : ern.x;
  float ernB = hh ? ern.w : ern.z;

  float sA = 0.f, sB = 0.f;
  float aA0 = 0.f, aA1 = 0.f, aB0 = 0.f, aB1 = 0.f;
  if (e0 < e1) {
    int sp = csrc[e0];
    float4 ep = reinterpret_cast<const float4*>(el)[sp];
    unsigned u0 = fb[(size_t)sp * 128 + lane];
    unsigned u1 = fb[(size_t)sp * 128 + 64 + lane];
    for (int t = e0; t < e1; ++t) {
      float4 ec = ep; unsigned v0 = u0, v1 = u1;
      if (t + 1 < e1) {
        int sn = csrc[t + 1];
        ep = reinterpret_cast<const float4*>(el)[sn];
        u0 = fb[(size_t)sn * 128 + lane];
        u1 = fb[(size_t)sn * 128 + 64 + lane];
      }
      float elA = hh ? ec.y : ec.x;
      float elB = hh ? ec.w : ec.z;
      float w, pA, pB;
      w = elA + ernA; w = fmaxf(w, 0.2f * w); pA = __expf(w); sA += pA;
      w = elB + ernB; w = fmaxf(w, 0.2f * w); pB = __expf(w); sB += pB;
      aA0 = fmaf(__uint_as_float(v0 << 16), pA, aA0);
      aA1 = fmaf(__uint_as_float(v0 & 0xffff0000u), pA, aA1);
      aB0 = fmaf(__uint_as_float(v1 << 16), pB, aB0);
      aB1 = fmaf(__uint_as_float(v1 & 0xffff0000u), pB, aB1);
    }
  }
  float iA = sA > 0.f ? 1.f / sA : 0.f;
  float iB = sB > 0.f ? 1.f / sB : 0.f;
  int c0 = 2 * lane, c2 = 128 + 2 * lane;
  float2 bb0 = *reinterpret_cast<const float2*>(bias + c0);
  float2 bb2 = *reinterpret_cast<const float2*>(bias + c2);
  float y0 = fmaxf(aA0 * iA + bb0.x, 0.f);
  float y1 = fmaxf(aA1 * iA + bb0.y, 0.f);
  float y2 = fmaxf(aB0 * iB + bb2.x, 0.f);
  float y3 = fmaxf(aB1 * iB + bb2.y, 0.f);
  float s = y0 + y1 + y2 + y3;
  float q = y0 * y0 + y1 * y1 + y2 * y2 + y3 * y3;
  s = wave_sum(s); q = wave_sum(q);
  float mu = s * (1.f / HID);
  float rs = rsqrtf(fmaxf(q * (1.f / HID) - mu * mu, 0.f) + 1e-5f);
  float2 gg0 = *reinterpret_cast<const float2*>(g + c0);
  float2 gg2 = *reinterpret_cast<const float2*>(g + c2);
  float2 ee0 = *reinterpret_cast<const float2*>(be + c0);
  float2 ee2 = *reinterpret_cast<const float2*>(be + c2);
  float h0 = (y0 - mu) * rs * gg0.x + ee0.x;
  float h1 = (y1 - mu) * rs * gg0.y + ee0.y;
  float h2 = (y2 - mu) * rs * gg2.x + ee2.x;
  float h3 = (y3 - mu) * rs * gg2.y + ee2.y;
  size_t base = (size_t)n * HID;
  *reinterpret_cast<float2*>(h + base + c0) = make_float2(h0, h1);
  *reinterpret_cast<float2*>(h + base + c2) = make_float2(h2, h3);

  if (hbd) {  // bf16 pack for next layer's MFMA GEMM (pair-adjacent already)
    hbd[(size_t)n * 128 + lane] = f2bf(h0) | (f2bf(h1) << 16);
    hbd[(size_t)n * 128 + 64 + lane] = f2bf(h2) | (f2bf(h3) << 16);
  }
  if (gw) {  // fused gate score (layer 1 only)
    float2 w0 = *reinterpret_cast<const float2*>(gw + c0);
    float2 w2 = *reinterpret_cast<const float2*>(gw + c2);
    float p = h0 * w0.x + h1 * w0.y + h2 * w2.x + h3 * w2.y;
    p = wave_sum(p);
    if (lane == 0) gate[n] = p + gb[0];
  }
}

// ---------- per-graph max of gate ----------
__global__ void k_gmax(const float* __restrict__ gate, const int* __restrict__ gid,
                       unsigned* __restrict__ gmax_u) {
  __shared__ unsigned sm[NB];
  int t = threadIdx.x;
  if (t < NB) sm[t] = 0u;
  __syncthreads();
  int n = blockIdx.x * blockDim.x + t;
  if (n < N_FACES) atomicMax(&sm[gid[n]], enc_ord(gate[n]));
  __syncthreads();
  if (t < NB && sm[t] != 0u) atomicMax(&gmax_u[t], sm[t]);
}

// ---------- parallel weighted pooling (unnormalized) ----------
#define PCHUNK 125
__global__ void k_psum(const float* __restrict__ h, const float* __restrict__ gate,
                       const int* __restrict__ gid, const unsigned* __restrict__ gmax_u,
                       float* __restrict__ praw, float* __restrict__ gs) {
  int t = threadIdx.x;
  int n0 = blockIdx.x * PCHUNK;
  int n1 = n0 + PCHUNK;
  if (n1 > N_FACES) n1 = N_FACES;
  if (n0 >= N_FACES) return;
  int cur = gid[n0];
  float gm = dec_ord(gmax_u[cur]);
  float acc = 0.f, wsum = 0.f;
  for (int n = n0; n < n1; ++n) {
    int g = gid[n];
    if (g != cur) {
      atomicAdd(&praw[cur * HID + t], acc);
      if (t == 0) atomicAdd(&gs[cur], wsum);
      acc = 0.f; wsum = 0.f; cur = g; gm = dec_ord(gmax_u[cur]);
    }
    float w = __expf(gate[n] - gm);
    acc += w * h[(size_t)n * HID + t];
    wsum += w;
  }
  atomicAdd(&praw[cur * HID + t], acc);
  if (t == 0) atomicAdd(&gs[cur], wsum);
}

__global__ void k_poolnorm(const float* __restrict__ praw, const float* __restrict__ gs,
                           float* __restrict__ pooled) {
  int b = blockIdx.x, c = threadIdx.x;
  pooled[b * HID + c] = praw[b * HID + c] / gs[b];
}

// ---------- output projection + LN ----------
__global__ void k_out(const float* __restrict__ pooled, const float* __restrict__ oW,
                      const float* __restrict__ oB, const float* __restrict__ oG,
                      const float* __restrict__ oBe, float* __restrict__ feat) {
  int b = blockIdx.x;
  int o = threadIdx.x;  // 512 threads
  int lane = o & 63, wid = o >> 6;
  __shared__ float p[HID];
  __shared__ float partS[8], partQ[8];
  __shared__ float shMu, shRs;
  if (o < HID) p[o] = pooled[b * HID + o];
  __syncthreads();
  float a = oB[o];
  for (int k = 0; k < HID; ++k) a += p[k] * oW[k * NOUT + o];
  float y = fmaxf(a, 0.f);
  float s = wave_sum(y), q = wave_sum(y * y);
  if (lane == 0) { partS[wid] = s; partQ[wid] = q; }
  __syncthreads();
  if (o == 0) {
    float S = 0.f, Q = 0.f;
#pragma unroll
    for (int i = 0; i < 8; ++i) { S += partS[i]; Q += partQ[i]; }
    float mu = S * (1.f / NOUT);
    shMu = mu;
    shRs = rsqrtf(fmaxf(Q * (1.f / NOUT) - mu * mu, 0.f) + 1e-5f);
  }
  __syncthreads();
  feat[b * NOUT + o] = (y - shMu) * shRs * oG[o] + oBe[o];
}

extern "C" void kernel_launch(void* const* d_in, const int* in_sizes, int n_in,
                              void* d_out, int out_size, void* d_ws, size_t ws_size,
                              hipStream_t stream) {
  (void)in_sizes; (void)n_in; (void)out_size; (void)ws_size;
  const float* x_face    = (const float*)d_in[0];
  const float* x_edge    = (const float*)d_in[1];
  const float* face_W    = (const float*)d_in[2];
  const float* face_b    = (const float*)d_in[3];
  const float* face_g    = (const float*)d_in[4];
  const float* face_beta = (const float*)d_in[5];
  const float* edge_W    = (const float*)d_in[6];
  const float* edge_b    = (const float*)d_in[7];
  const float* edge_g    = (const float*)d_in[8];
  const float* edge_beta = (const float*)d_in[9];
  const float* g0_W      = (const float*)d_in[10];
  const float* g0_al     = (const float*)d_in[11];
  const float* g0_ar     = (const float*)d_in[12];
  const float* g0_bias   = (const float*)d_in[13];
  const float* g0_g      = (const float*)d_in[14];
  const float* g0_beta   = (const float*)d_in[15];
  const float* g1_W      = (const float*)d_in[16];
  const float* g1_al     = (const float*)d_in[17];
  const float* g1_ar     = (const float*)d_in[18];
  const float* g1_bias   = (const float*)d_in[19];
  const float* g1_g      = (const float*)d_in[20];
  const float* g1_beta   = (const float*)d_in[21];
  const float* gate_W    = (const float*)d_in[22];
  const float* gate_b    = (const float*)d_in[23];
  const float* out_W     = (const float*)d_in[24];
  const float* out_b     = (const float*)d_in[25];
  const float* out_g     = (const float*)d_in[26];
  const float* out_beta  = (const float*)d_in[27];
  const int*   src       = (const int*)d_in[28];
  const int*   dst       = (const int*)d_in[29];
  const int*   gid       = (const int*)d_in[30];

  char* ws = (char*)d_ws;
  size_t off = 0;
  auto take = [&](size_t bytes) -> char* {
    char* pp = ws + off;
    off += (bytes + 255) & ~(size_t)255;
    return pp;
  };
  int*      cnt      = (int*)take((size_t)N_FACES * 4);
  int*      fill     = (int*)take((size_t)N_FACES * 4);
  int*      row_ptr  = (int*)take((size_t)(N_FACES + 1) * 4);
  int*      bsum     = (int*)take((size_t)SCAN_NB * 4);
  int*      csr_src  = (int*)take((size_t)N_EDGES * 4);
  uint4*    rec16    = (uint4*)take((size_t)N_EDGES * 16);
  uint4*    Wp0      = (uint4*)take((size_t)8192 * 16);
  uint4*    Wp1      = (uint4*)take((size_t)8192 * 16);
  unsigned* gmax_u   = (unsigned*)take(64);
  float*    gs       = (float*)take(64);
  float*    praw     = (float*)take((size_t)NB * HID * 4);
  float*    el       = (float*)take((size_t)N_FACES * 4 * 4);
  float*    er       = (float*)take((size_t)N_FACES * 4 * 4);
  float*    gate     = (float*)take((size_t)N_FACES * 4);
  unsigned* fbuf     = (unsigned*)take((size_t)N_FACES * 128 * 4);
  unsigned* hbd      = (unsigned*)take((size_t)N_FACES * 128 * 4);

  float* outp   = (float*)d_out;
  float* feat   = outp;
  float* h      = outp + NB * NOUT;
  float* pooled = outp + NB * NOUT + (size_t)N_FACES * HID;

  hipMemsetAsync(cnt, 0, (size_t)N_FACES * 4, stream);
  hipMemsetAsync(fill, 0, (size_t)N_FACES * 4, stream);
  hipMemsetAsync(gmax_u, 0, 64, stream);
  hipMemsetAsync(gs, 0, 64, stream);
  hipMemsetAsync(praw, 0, (size_t)NB * HID * 4, stream);

  k_hist<<<(N_EDGES + 255) / 256, 256, 0, stream>>>(dst, cnt);
  k_scan1<<<SCAN_NB, SCAN_B, 0, stream>>>(cnt, bsum);
  k_scan2<<<1, 64, 0, stream>>>(bsum);
  k_scan3<<<SCAN_NB, SCAN_B, 0, stream>>>(cnt, bsum, row_ptr);
  k_packW<<<32, 256, 0, stream>>>(g0_W, Wp0);
  k_packW<<<32, 256, 0, stream>>>(g1_W, Wp1);
  k_scatter<<<N_EDGES / 64, 256, 0, stream>>>(dst, src, x_edge, row_ptr,
                                              edge_W, edge_b, fill, rec16, csr_src);

  k_encode<<<N_FACES / 4, 256, 0, stream>>>(x_face, rec16, face_W, face_b, face_g, face_beta,
                                            edge_W, edge_b, edge_g, edge_beta,
                                            row_ptr, h, hbd);
  // GAT layer 0
  k_gemm_mfma<<<(NT + 3) / 4, 256, 0, stream>>>(hbd, Wp0, g0_al, g0_ar, fbuf, el, er);
  k_gat<<<N_FACES / 4, 256, 0, stream>>>(fbuf, el, er, row_ptr, csr_src,
                                         g0_bias, g0_g, g0_beta, h, hbd,
                                         nullptr, nullptr, nullptr);
  // GAT layer 1 (+ fused gate scores)
  k_gemm_mfma<<<(NT + 3) / 4, 256, 0, stream>>>(hbd, Wp1, g1_al, g1_ar, fbuf, el, er);
  k_gat<<<N_FACES / 4, 256, 0, stream>>>(fbuf, el, er, row_ptr, csr_src,
                                         g1_bias, g1_g, g1_beta, h, nullptr,
                                         gate_W, gate_b, gate);
  // pooling + output head
  k_gmax<<<(N_FACES + 255) / 256, 256, 0, stream>>>(gate, gid, gmax_u);
  k_psum<<<(N_FACES + PCHUNK - 1) / PCHUNK, 256, 0, stream>>>(h, gate, gid, gmax_u, praw, gs);
  k_poolnorm<<<NB, HID, 0, stream>>>(praw, gs, pooled);
  k_out<<<NB, NOUT, 0, stream>>>(pooled, out_W, out_b, out_g, out_beta, feat);
}

// Round 10
// 539.760 us; speedup vs baseline: 1.6762x; 1.1856x over previous
//
#include <hip/hip_runtime.h>

#define N_FACES 50000
#define N_EDGES 800000
#define NB      16
#define HID     256
#define NOUT    512
#define SCAN_B  1024
#define SCAN_NB ((N_FACES + SCAN_B - 1) / SCAN_B)
#define NT      (N_FACES / 16)   // 3125 MFMA node-tiles (exact)

typedef __attribute__((ext_vector_type(8))) short short8v;
typedef __attribute__((ext_vector_type(4))) float float4v;
union U8 { uint4 u; short8v s; };

// ---------- wave helpers ----------
__device__ __forceinline__ float wave_sum(float v) {
#pragma unroll
  for (int o = 32; o; o >>= 1) v += __shfl_xor(v, o, 64);
  return v;
}

// ---------- order-preserving float<->uint encoding (for atomicMax) ----------
__device__ __forceinline__ unsigned enc_ord(float v) {
  unsigned b = __float_as_uint(v);
  return (b & 0x80000000u) ? ~b : (b | 0x80000000u);
}
__device__ __forceinline__ float dec_ord(unsigned e) {
  unsigned b = (e & 0x80000000u) ? (e ^ 0x80000000u) : ~e;
  return __uint_as_float(b);
}

// RNE float->bf16 (finite inputs)
__device__ __forceinline__ unsigned f2bf(float x) {
  unsigned u = __float_as_uint(x);
  return (u + 0x7fffu + ((u >> 16) & 1u)) >> 16;
}
__device__ __forceinline__ float bf_lo(unsigned u) { return __uint_as_float(u << 16); }
__device__ __forceinline__ float bf_hi(unsigned u) { return __uint_as_float(u & 0xffff0000u); }

// ---------- CSR build ----------
__global__ void k_hist(const int* __restrict__ dst, int* __restrict__ cnt) {
  int e = blockIdx.x * blockDim.x + threadIdx.x;
  if (e < N_EDGES) atomicAdd(&cnt[dst[e]], 1);
}

__global__ void k_scan1(const int* __restrict__ cnt, int* __restrict__ bsum) {
  __shared__ int sh[SCAN_B];
  int i = blockIdx.x * SCAN_B + threadIdx.x;
  sh[threadIdx.x] = (i < N_FACES) ? cnt[i] : 0;
  __syncthreads();
  for (int off = SCAN_B / 2; off; off >>= 1) {
    if (threadIdx.x < off) sh[threadIdx.x] += sh[threadIdx.x + off];
    __syncthreads();
  }
  if (threadIdx.x == 0) bsum[blockIdx.x] = sh[0];
}

__global__ void k_scan2(int* __restrict__ bsum) {  // nb <= 64, one wave
  int t = threadIdx.x;
  int v = (t < SCAN_NB) ? bsum[t] : 0;
  int inc = v;
#pragma unroll
  for (int off = 1; off < 64; off <<= 1) {
    int u = __shfl_up(inc, off, 64);
    if (t >= off) inc += u;
  }
  if (t < SCAN_NB) bsum[t] = inc - v;  // exclusive
}

__global__ void k_scan3(const int* __restrict__ cnt, const int* __restrict__ bsum,
                        int* __restrict__ row_ptr) {
  __shared__ int sh[SCAN_B];
  int i = blockIdx.x * SCAN_B + threadIdx.x;
  int v = (i < N_FACES) ? cnt[i] : 0;
  sh[threadIdx.x] = v;
  __syncthreads();
  for (int off = 1; off < SCAN_B; off <<= 1) {
    int x = (threadIdx.x >= off) ? sh[threadIdx.x - off] : 0;
    __syncthreads();
    sh[threadIdx.x] += x;
    __syncthreads();
  }
  if (i < N_FACES) row_ptr[i] = bsum[blockIdx.x] + sh[threadIdx.x] - v;
  if (i == 0) row_ptr[N_FACES] = N_EDGES;
}

// ---------- scatter: 4 lanes per edge; bank-conflict-free rotated LDS reads ----------
__global__ void k_scatter(const int* __restrict__ dst, const int* __restrict__ src,
                          const float* __restrict__ xe, const int* __restrict__ row_ptr,
                          const float* __restrict__ eW, const float* __restrict__ eB,
                          int* __restrict__ fill, uint4* __restrict__ rec16,
                          int* __restrict__ csr_src) {
  __shared__ float sw[6][HID];
  __shared__ float sb[HID];
  int t = threadIdx.x;
  for (int i = t; i < 6 * HID; i += 256) sw[i / HID][i % HID] = eW[i];
  for (int i = t; i < HID; i += 256) sb[i] = eB[i];
  __syncthreads();

  int e = blockIdx.x * 64 + (t >> 2);   // grid sized exactly: 12500 blocks
  int seg = t & 3;
  unsigned zb[6];
  float z[6];
#pragma unroll
  for (int k = 0; k < 6; ++k) {
    zb[k] = f2bf(xe[(size_t)e * 6 + k]);
    z[k] = __uint_as_float(zb[k] << 16);   // stats from bf16-rounded z (consistent)
  }
  int pos = 0;
  if (seg == 0) {
    int d = dst[e];
    int p = atomicAdd(&fill[d], 1);
    pos = row_ptr[d] + p;
  }
  pos = __shfl(pos, (t & 63) & ~3, 64);

  float s1 = 0.f, s2 = 0.f;
  int cbase = seg * 64;
  int rot = 4 * seg;  // rotate start so the 4 segs hit distinct banks (4i+4s mod 32)
#pragma unroll 4
  for (int ii = 0; ii < 16; ++ii) {
    int c = cbase + ((4 * ii + rot) & 63);
    float4 w4 = *reinterpret_cast<const float4*>(&sb[c]);
#pragma unroll
    for (int k = 0; k < 6; ++k) {
      float4 m4 = *reinterpret_cast<const float4*>(&sw[k][c]);
      w4.x = fmaf(z[k], m4.x, w4.x); w4.y = fmaf(z[k], m4.y, w4.y);
      w4.z = fmaf(z[k], m4.z, w4.z); w4.w = fmaf(z[k], m4.w, w4.w);
    }
    w4.x = fmaxf(w4.x, 0.f); w4.y = fmaxf(w4.y, 0.f);
    w4.z = fmaxf(w4.z, 0.f); w4.w = fmaxf(w4.w, 0.f);
    s1 += (w4.x + w4.y) + (w4.z + w4.w);
    s2 += (w4.x * w4.x + w4.y * w4.y) + (w4.z * w4.z + w4.w * w4.w);
  }
  s1 += __shfl_xor(s1, 1, 64); s1 += __shfl_xor(s1, 2, 64);
  s2 += __shfl_xor(s2, 1, 64); s2 += __shfl_xor(s2, 2, 64);
  if (seg == 0) {
    float mu = s1 * (1.f / HID);
    float rs = rsqrtf(fmaxf(s2 * (1.f / HID) - mu * mu, 0.f) + 1e-5f);
    csr_src[pos] = src[e];
    rec16[pos] = make_uint4(zb[0] | (zb[1] << 16), zb[2] | (zb[3] << 16),
                            zb[4] | (zb[5] << 16), f2bf(mu) | (f2bf(rs) << 16));
  }
}

// ---------- encoders + mean aggregation; writes h fp32 + packed bf16 hbd ----------
__global__ void k_encode(const float* __restrict__ xf, const uint4* __restrict__ rec16,
                         const float* __restrict__ fW, const float* __restrict__ fB,
                         const float* __restrict__ fG, const float* __restrict__ fBe,
                         const float* __restrict__ eW, const float* __restrict__ eB,
                         const float* __restrict__ eG, const float* __restrict__ eBe,
                         const int* __restrict__ row_ptr, float* __restrict__ h,
                         unsigned* __restrict__ hbd) {
  int lane = threadIdx.x & 63;
  int n = blockIdx.x * 4 + (threadIdx.x >> 6);
  if (n >= N_FACES) return;

  // face encoder
  float x[7];
#pragma unroll
  for (int k = 0; k < 7; ++k) x[k] = xf[n * 7 + k];
  float y[4];
#pragma unroll
  for (int j = 0; j < 4; ++j) {
    int c = lane + 64 * j;
    float a = fB[c];
#pragma unroll
    for (int k = 0; k < 7; ++k) a += x[k] * fW[k * HID + c];
    y[j] = fmaxf(a, 0.f);
  }
  float s = y[0] + y[1] + y[2] + y[3];
  float s2 = y[0] * y[0] + y[1] * y[1] + y[2] * y[2] + y[3] * y[3];
  s = wave_sum(s); s2 = wave_sum(s2);
  float mu = s * (1.f / HID);
  float rs = rsqrtf(fmaxf(s2 * (1.f / HID) - mu * mu, 0.f) + 1e-5f);
  float hv[4];
#pragma unroll
  for (int j = 0; j < 4; ++j) {
    int c = lane + 64 * j;
    hv[j] = (y[j] - mu) * rs * fG[c] + fBe[c];
  }

  // hoist edge-encoder params (loop-invariant)
  float ew[6][4], eb[4], eg[4], ebe[4];
#pragma unroll
  for (int j = 0; j < 4; ++j) {
    int c = lane + 64 * j;
    eb[j] = eB[c]; eg[j] = eG[c]; ebe[j] = eBe[c];
#pragma unroll
    for (int k = 0; k < 6; ++k) ew[k][j] = eW[k * HID + c];
  }

  int e0 = row_ptr[n], e1 = row_ptr[n + 1];
  float acc[4] = {0.f, 0.f, 0.f, 0.f};
  uint4 pf;
  if (e0 < e1) pf = rec16[e0];
  for (int t = e0; t < e1; ++t) {
    uint4 cu = pf;
    if (t + 1 < e1) pf = rec16[t + 1];
    float z0 = bf_lo(cu.x), z1 = bf_hi(cu.x), z2 = bf_lo(cu.y), z3 = bf_hi(cu.y);
    float z4 = bf_lo(cu.z), z5 = bf_hi(cu.z);
    float emu = bf_lo(cu.w), ers = bf_hi(cu.w);
#pragma unroll
    for (int j = 0; j < 4; ++j) {
      float a = eb[j];
      a = fmaf(z0, ew[0][j], a); a = fmaf(z1, ew[1][j], a);
      a = fmaf(z2, ew[2][j], a); a = fmaf(z3, ew[3][j], a);
      a = fmaf(z4, ew[4][j], a); a = fmaf(z5, ew[5][j], a);
      a = fmaxf(a, 0.f);
      acc[j] += (a - emu) * (ers * eg[j]) + ebe[j];
    }
  }
  float inv = (e1 > e0) ? 1.f / (float)(e1 - e0) : 0.f;
  float hval[4];
#pragma unroll
  for (int j = 0; j < 4; ++j) {
    hval[j] = hv[j] + acc[j] * inv;
    h[(size_t)n * HID + lane + 64 * j] = hval[j];
  }
  // packed bf16 h: dword idx = global_col/2; lane l owns cols l+64j, partner l^1
#pragma unroll
  for (int j = 0; j < 4; ++j) {
    float other = __shfl_xor(hval[j], 1, 64);
    if (!(lane & 1))
      hbd[(size_t)n * 128 + 32 * j + (lane >> 1)] = f2bf(hval[j]) | (f2bf(other) << 16);
  }
}

// ---------- pack W (fp32 [K][256]) into MFMA B-fragment layout (bf16) ----------
__global__ void k_packW(const float* __restrict__ W, uint4* __restrict__ Wp) {
  int i = blockIdx.x * 256 + threadIdx.x;  // 16ct * 8ks * 64lane = 8192
  int lane = i & 63, ks = (i >> 6) & 7, ct = i >> 9;
  int kbase = ks * 32 + (lane >> 4) * 8;
  int col = ct * 16 + (lane & 15);
  unsigned d[4];
#pragma unroll
  for (int r = 0; r < 4; ++r) {
    unsigned lo = f2bf(W[(size_t)(kbase + 2 * r) * HID + col]);
    unsigned hi = f2bf(W[(size_t)(kbase + 2 * r + 1) * HID + col]);
    d[r] = lo | (hi << 16);
  }
  Wp[i] = make_uint4(d[0], d[1], d[2], d[3]);
}

// ---------- MFMA GEMM: f=h@W (bf16), fused el/er + fb-layout write ----------
__global__ void k_gemm_mfma(const unsigned* __restrict__ hbd, const uint4* __restrict__ Wp,
                            const float* __restrict__ al, const float* __restrict__ ar,
                            unsigned* __restrict__ fb, float* __restrict__ el,
                            float* __restrict__ er) {
  int tile = blockIdx.x * 4 + (threadIdx.x >> 6);
  if (tile >= NT) return;
  int lane = threadIdx.x & 63;
  int c = lane & 15;   // A-row / B,D-col within tile
  int kg = lane >> 4;  // k-group
  int n0 = tile * 16;

  uint4 afrag[8];
#pragma unroll
  for (int ks = 0; ks < 8; ++ks)
    afrag[ks] = *reinterpret_cast<const uint4*>(hbd + (size_t)(n0 + c) * 128 + ks * 16 + kg * 4);

  float4v acc[16];
#pragma unroll
  for (int ct = 0; ct < 16; ++ct) acc[ct] = (float4v){0.f, 0.f, 0.f, 0.f};
#pragma unroll
  for (int ct = 0; ct < 16; ++ct) {
#pragma unroll
    for (int ks = 0; ks < 8; ++ks) {
      U8 a, b;
      a.u = afrag[ks];
      b.u = Wp[(ct * 8 + ks) * 64 + lane];
      acc[ct] = __builtin_amdgcn_mfma_f32_16x16x32_bf16(a.s, b.s, acc[ct], 0, 0, 0);
    }
  }

  // fb write (k_gat layout: dword = global_col/2): pack pair via shfl_xor(1)
#pragma unroll
  for (int ct = 0; ct < 16; ++ct) {
#pragma unroll
    for (int reg = 0; reg < 4; ++reg) {
      float v = acc[ct][reg];
      float vo = __shfl_xor(v, 1, 64);
      if (!(lane & 1)) {
        int nd = n0 + kg * 4 + reg;
        fb[(size_t)nd * 128 + ct * 8 + (c >> 1)] = f2bf(v) | (f2bf(vo) << 16);
      }
    }
  }

  // el/er: reduce over 16 cols per tile-col-group; head = ct>>2
  float alr[16], arr[16];
#pragma unroll
  for (int ct = 0; ct < 16; ++ct) {
    alr[ct] = al[ct * 16 + c];
    arr[ct] = ar[ct * 16 + c];
  }
#pragma unroll
  for (int hd = 0; hd < 4; ++hd) {
#pragma unroll
    for (int reg = 0; reg < 4; ++reg) {
      float pl = 0.f, pr = 0.f;
#pragma unroll
      for (int q = 0; q < 4; ++q) {
        int ct = hd * 4 + q;
        pl = fmaf(acc[ct][reg], alr[ct], pl);
        pr = fmaf(acc[ct][reg], arr[ct], pr);
      }
#pragma unroll
      for (int o = 1; o < 16; o <<= 1) {
        pl += __shfl_xor(pl, o, 64);
        pr += __shfl_xor(pr, o, 64);
      }
      if (c == 0) {
        int nd = n0 + kg * 4 + reg;
        el[nd * 4 + hd] = pl;
        er[nd * 4 + hd] = pr;
      }
    }
  }
}

// ---------- GAT: bf16 f gather; optional hbd pack-out (layer0) and fused gate (layer1) ----------
__global__ void k_gat(const unsigned* __restrict__ fb, const float* __restrict__ el,
                      const float* __restrict__ er, const int* __restrict__ row_ptr,
                      const int* __restrict__ csrc,
                      const float* __restrict__ bias, const float* __restrict__ g,
                      const float* __restrict__ be, float* __restrict__ h,
                      unsigned* __restrict__ hbd,
                      const float* __restrict__ gw, const float* __restrict__ gb,
                      float* __restrict__ gate) {
  int lane = threadIdx.x & 63;
  int n = blockIdx.x * 4 + (threadIdx.x >> 6);
  if (n >= N_FACES) return;
  int e0 = row_ptr[n], e1 = row_ptr[n + 1];
  float4 ern = reinterpret_cast<const float4*>(er)[n];
  int hh = lane >> 5;  // this lane's heads: hh and hh+2
  float ernA = hh ? ern.y : ern.x;
  float ernB = hh ? ern.w : ern.z;

  float sA = 0.f, sB = 0.f;
  float aA0 = 0.f, aA1 = 0.f, aB0 = 0.f, aB1 = 0.f;
  if (e0 < e1) {
    int sp = csrc[e0];
    float4 ep = reinterpret_cast<const float4*>(el)[sp];
    unsigned u0 = fb[(size_t)sp * 128 + lane];
    unsigned u1 = fb[(size_t)sp * 128 + 64 + lane];
    for (int t = e0; t < e1; ++t) {
      float4 ec = ep; unsigned v0 = u0, v1 = u1;
      if (t + 1 < e1) {
        int sn = csrc[t + 1];
        ep = reinterpret_cast<const float4*>(el)[sn];
        u0 = fb[(size_t)sn * 128 + lane];
        u1 = fb[(size_t)sn * 128 + 64 + lane];
      }
      float elA = hh ? ec.y : ec.x;
      float elB = hh ? ec.w : ec.z;
      float w, pA, pB;
      w = elA + ernA; w = fmaxf(w, 0.2f * w); pA = __expf(w); sA += pA;
      w = elB + ernB; w = fmaxf(w, 0.2f * w); pB = __expf(w); sB += pB;
      aA0 = fmaf(__uint_as_float(v0 << 16), pA, aA0);
      aA1 = fmaf(__uint_as_float(v0 & 0xffff0000u), pA, aA1);
      aB0 = fmaf(__uint_as_float(v1 << 16), pB, aB0);
      aB1 = fmaf(__uint_as_float(v1 & 0xffff0000u), pB, aB1);
    }
  }
  float iA = sA > 0.f ? 1.f / sA : 0.f;
  float iB = sB > 0.f ? 1.f / sB : 0.f;
  int c0 = 2 * lane, c2 = 128 + 2 * lane;
  float2 bb0 = *reinterpret_cast<const float2*>(bias + c0);
  float2 bb2 = *reinterpret_cast<const float2*>(bias + c2);
  float y0 = fmaxf(aA0 * iA + bb0.x, 0.f);
  float y1 = fmaxf(aA1 * iA + bb0.y, 0.f);
  float y2 = fmaxf(aB0 * iB + bb2.x, 0.f);
  float y3 = fmaxf(aB1 * iB + bb2.y, 0.f);
  float s = y0 + y1 + y2 + y3;
  float q = y0 * y0 + y1 * y1 + y2 * y2 + y3 * y3;
  s = wave_sum(s); q = wave_sum(q);
  float mu = s * (1.f / HID);
  float rs = rsqrtf(fmaxf(q * (1.f / HID) - mu * mu, 0.f) + 1e-5f);
  float2 gg0 = *reinterpret_cast<const float2*>(g + c0);
  float2 gg2 = *reinterpret_cast<const float2*>(g + c2);
  float2 ee0 = *reinterpret_cast<const float2*>(be + c0);
  float2 ee2 = *reinterpret_cast<const float2*>(be + c2);
  float h0 = (y0 - mu) * rs * gg0.x + ee0.x;
  float h1 = (y1 - mu) * rs * gg0.y + ee0.y;
  float h2 = (y2 - mu) * rs * gg2.x + ee2.x;
  float h3 = (y3 - mu) * rs * gg2.y + ee2.y;
  size_t base = (size_t)n * HID;
  *reinterpret_cast<float2*>(h + base + c0) = make_float2(h0, h1);
  *reinterpret_cast<float2*>(h + base + c2) = make_float2(h2, h3);

  if (hbd) {  // bf16 pack for next layer's MFMA GEMM (pair-adjacent already)
    hbd[(size_t)n * 128 + lane] = f2bf(h0) | (f2bf(h1) << 16);
    hbd[(size_t)n * 128 + 64 + lane] = f2bf(h2) | (f2bf(h3) << 16);
  }
  if (gw) {  // fused gate score (layer 1 only)
    float2 w0 = *reinterpret_cast<const float2*>(gw + c0);
    float2 w2 = *reinterpret_cast<const float2*>(gw + c2);
    float p = h0 * w0.x + h1 * w0.y + h2 * w2.x + h3 * w2.y;
    p = wave_sum(p);
    if (lane == 0) gate[n] = p + gb[0];
  }
}

// ---------- per-graph max of gate ----------
__global__ void k_gmax(const float* __restrict__ gate, const int* __restrict__ gid,
                       unsigned* __restrict__ gmax_u) {
  __shared__ unsigned sm[NB];
  int t = threadIdx.x;
  if (t < NB) sm[t] = 0u;
  __syncthreads();
  int n = blockIdx.x * blockDim.x + t;
  if (n < N_FACES) atomicMax(&sm[gid[n]], enc_ord(gate[n]));
  __syncthreads();
  if (t < NB && sm[t] != 0u) atomicMax(&gmax_u[t], sm[t]);
}

// ---------- parallel weighted pooling (unnormalized) ----------
#define PCHUNK 125
__global__ void k_psum(const float* __restrict__ h, const float* __restrict__ gate,
                       const int* __restrict__ gid, const unsigned* __restrict__ gmax_u,
                       float* __restrict__ praw, float* __restrict__ gs) {
  int t = threadIdx.x;
  int n0 = blockIdx.x * PCHUNK;
  int n1 = n0 + PCHUNK;
  if (n1 > N_FACES) n1 = N_FACES;
  if (n0 >= N_FACES) return;
  int cur = gid[n0];
  float gm = dec_ord(gmax_u[cur]);
  float acc = 0.f, wsum = 0.f;
  for (int n = n0; n < n1; ++n) {
    int g = gid[n];
    if (g != cur) {
      atomicAdd(&praw[cur * HID + t], acc);
      if (t == 0) atomicAdd(&gs[cur], wsum);
      acc = 0.f; wsum = 0.f; cur = g; gm = dec_ord(gmax_u[cur]);
    }
    float w = __expf(gate[n] - gm);
    acc += w * h[(size_t)n * HID + t];
    wsum += w;
  }
  atomicAdd(&praw[cur * HID + t], acc);
  if (t == 0) atomicAdd(&gs[cur], wsum);
}

__global__ void k_poolnorm(const float* __restrict__ praw, const float* __restrict__ gs,
                           float* __restrict__ pooled) {
  int b = blockIdx.x, c = threadIdx.x;
  pooled[b * HID + c] = praw[b * HID + c] / gs[b];
}

// ---------- output projection + LN ----------
__global__ void k_out(const float* __restrict__ pooled, const float* __restrict__ oW,
                      const float* __restrict__ oB, const float* __restrict__ oG,
                      const float* __restrict__ oBe, float* __restrict__ feat) {
  int b = blockIdx.x;
  int o = threadIdx.x;  // 512 threads
  int lane = o & 63, wid = o >> 6;
  __shared__ float p[HID];
  __shared__ float partS[8], partQ[8];
  __shared__ float shMu, shRs;
  if (o < HID) p[o] = pooled[b * HID + o];
  __syncthreads();
  float a = oB[o];
  for (int k = 0; k < HID; ++k) a += p[k] * oW[k * NOUT + o];
  float y = fmaxf(a, 0.f);
  float s = wave_sum(y), q = wave_sum(y * y);
  if (lane == 0) { partS[wid] = s; partQ[wid] = q; }
  __syncthreads();
  if (o == 0) {
    float S = 0.f, Q = 0.f;
#pragma unroll
    for (int i = 0; i < 8; ++i) { S += partS[i]; Q += partQ[i]; }
    float mu = S * (1.f / NOUT);
    shMu = mu;
    shRs = rsqrtf(fmaxf(Q * (1.f / NOUT) - mu * mu, 0.f) + 1e-5f);
  }
  __syncthreads();
  feat[b * NOUT + o] = (y - shMu) * shRs * oG[o] + oBe[o];
}

extern "C" void kernel_launch(void* const* d_in, const int* in_sizes, int n_in,
                              void* d_out, int out_size, void* d_ws, size_t ws_size,
                              hipStream_t stream) {
  (void)in_sizes; (void)n_in; (void)out_size; (void)ws_size;
  const float* x_face    = (const float*)d_in[0];
  const float* x_edge    = (const float*)d_in[1];
  const float* face_W    = (const float*)d_in[2];
  const float* face_b    = (const float*)d_in[3];
  const float* face_g    = (const float*)d_in[4];
  const float* face_beta = (const float*)d_in[5];
  const float* edge_W    = (const float*)d_in[6];
  const float* edge_b    = (const float*)d_in[7];
  const float* edge_g    = (const float*)d_in[8];
  const float* edge_beta = (const float*)d_in[9];
  const float* g0_W      = (const float*)d_in[10];
  const float* g0_al     = (const float*)d_in[11];
  const float* g0_ar     = (const float*)d_in[12];
  const float* g0_bias   = (const float*)d_in[13];
  const float* g0_g      = (const float*)d_in[14];
  const float* g0_beta   = (const float*)d_in[15];
  const float* g1_W      = (const float*)d_in[16];
  const float* g1_al     = (const float*)d_in[17];
  const float* g1_ar     = (const float*)d_in[18];
  const float* g1_bias   = (const float*)d_in[19];
  const float* g1_g      = (const float*)d_in[20];
  const float* g1_beta   = (const float*)d_in[21];
  const float* gate_W    = (const float*)d_in[22];
  const float* gate_b    = (const float*)d_in[23];
  const float* out_W     = (const float*)d_in[24];
  const float* out_b     = (const float*)d_in[25];
  const float* out_g     = (const float*)d_in[26];
  const float* out_beta  = (const float*)d_in[27];
  const int*   src       = (const int*)d_in[28];
  const int*   dst       = (const int*)d_in[29];
  const int*   gid       = (const int*)d_in[30];

  char* ws = (char*)d_ws;
  size_t off = 0;
  auto take = [&](size_t bytes) -> char* {
    char* pp = ws + off;
    off += (bytes + 255) & ~(size_t)255;
    return pp;
  };
  int*      cnt      = (int*)take((size_t)N_FACES * 4);
  int*      fill     = (int*)take((size_t)N_FACES * 4);
  int*      row_ptr  = (int*)take((size_t)(N_FACES + 1) * 4);
  int*      bsum     = (int*)take((size_t)SCAN_NB * 4);
  int*      csr_src  = (int*)take((size_t)N_EDGES * 4);
  uint4*    rec16    = (uint4*)take((size_t)N_EDGES * 16);
  uint4*    Wp0      = (uint4*)take((size_t)8192 * 16);
  uint4*    Wp1      = (uint4*)take((size_t)8192 * 16);
  unsigned* gmax_u   = (unsigned*)take(64);
  float*    gs       = (float*)take(64);
  float*    praw     = (float*)take((size_t)NB * HID * 4);
  float*    el       = (float*)take((size_t)N_FACES * 4 * 4);
  float*    er       = (float*)take((size_t)N_FACES * 4 * 4);
  float*    gate     = (float*)take((size_t)N_FACES * 4);
  unsigned* fbuf     = (unsigned*)take((size_t)N_FACES * 128 * 4);
  unsigned* hbd      = (unsigned*)take((size_t)N_FACES * 128 * 4);

  float* outp   = (float*)d_out;
  float* feat   = outp;
  float* h      = outp + NB * NOUT;
  float* pooled = outp + NB * NOUT + (size_t)N_FACES * HID;

  hipMemsetAsync(cnt, 0, (size_t)N_FACES * 4, stream);
  hipMemsetAsync(fill, 0, (size_t)N_FACES * 4, stream);
  hipMemsetAsync(gmax_u, 0, 64, stream);
  hipMemsetAsync(gs, 0, 64, stream);
  hipMemsetAsync(praw, 0, (size_t)NB * HID * 4, stream);

  k_hist<<<(N_EDGES + 255) / 256, 256, 0, stream>>>(dst, cnt);
  k_scan1<<<SCAN_NB, SCAN_B, 0, stream>>>(cnt, bsum);
  k_scan2<<<1, 64, 0, stream>>>(bsum);
  k_scan3<<<SCAN_NB, SCAN_B, 0, stream>>>(cnt, bsum, row_ptr);
  k_packW<<<32, 256, 0, stream>>>(g0_W, Wp0);
  k_packW<<<32, 256, 0, stream>>>(g1_W, Wp1);
  k_scatter<<<N_EDGES / 64, 256, 0, stream>>>(dst, src, x_edge, row_ptr,
                                              edge_W, edge_b, fill, rec16, csr_src);

  k_encode<<<N_FACES / 4, 256, 0, stream>>>(x_face, rec16, face_W, face_b, face_g, face_beta,
                                            edge_W, edge_b, edge_g, edge_beta,
                                            row_ptr, h, hbd);
  // GAT layer 0
  k_gemm_mfma<<<(NT + 3) / 4, 256, 0, stream>>>(hbd, Wp0, g0_al, g0_ar, fbuf, el, er);
  k_gat<<<N_FACES / 4, 256, 0, stream>>>(fbuf, el, er, row_ptr, csr_src,
                                         g0_bias, g0_g, g0_beta, h, hbd,
                                         nullptr, nullptr, nullptr);
  // GAT layer 1 (+ fused gate scores)
  k_gemm_mfma<<<(NT + 3) / 4, 256, 0, stream>>>(hbd, Wp1, g1_al, g1_ar, fbuf, el, er);
  k_gat<<<N_FACES / 4, 256, 0, stream>>>(fbuf, el, er, row_ptr, csr_src,
                                         g1_bias, g1_g, g1_beta, h, nullptr,
                                         gate_W, gate_b, gate);
  // pooling + output head
  k_gmax<<<(N_FACES + 255) / 256, 256, 0, stream>>>(gate, gid, gmax_u);
  k_psum<<<(N_FACES + PCHUNK - 1) / PCHUNK, 256, 0, stream>>>(h, gate, gid, gmax_u, praw, gs);
  k_poolnorm<<<NB, HID, 0, stream>>>(praw, gs, pooled);
  k_out<<<NB, NOUT, 0, stream>>>(pooled, out_W, out_b, out_g, out_beta, feat);
}